// Round 4
// baseline (134.149 us; speedup 1.0000x reference)
//
#include <hip/hip_runtime.h>

#define NB 512

// ---- LDS arena (floats), total 12928 = 51712 B ----
// S[32][132] @0 (4224)  -> K[32][68]@0, Q[32][68]@2176 -> AA@0, AP@2176
// ACT[32][16] @4224 (512), POL @4736 (512)
// E[32][68] @5248 (2176) -> NF @5248
// EA[32][68] @7424 (2176) -> H @7424
// EP[32][68] @9600 (2176)
// WT[32][36] @11776 (1152)
#define S_O    0
#define K_O    0
#define Q_O    2176
#define AA_O   0
#define AP_O   2176
#define ACT_O  4224
#define POL_O  4736
#define E_O    5248
#define NF_O   5248
#define EA_O   7424
#define H_O    7424
#define EP_O   9600
#define WT_O   11776
#define LDSF   12928

__device__ __forceinline__ float dot4(float4 a, float4 b, float acc) {
    acc = fmaf(a.x, b.x, acc);
    acc = fmaf(a.y, b.y, acc);
    acc = fmaf(a.z, b.z, acc);
    acc = fmaf(a.w, b.w, acc);
    return acc;
}
__device__ __forceinline__ float fast_tanh(float x) {
    float xc = fminf(fmaxf(x, -9.0f), 9.0f);
    float e = __expf(2.0f * xc);
    return (e - 1.0f) * __builtin_amdgcn_rcpf(e + 1.0f);
}

__global__ void __launch_bounds__(256)
critic_fused(const float* __restrict__ states, const float* __restrict__ policies,
             const float* __restrict__ actions,
             const float* __restrict__ W_obs, const float* __restrict__ b_obs,
             const float* __restrict__ W_oa,  const float* __restrict__ b_oa,
             const float* __restrict__ W_key, const float* __restrict__ W_query,
             const float* __restrict__ W_av,  const float* __restrict__ W_f1,
             const float* __restrict__ W_f2,
             float* __restrict__ out_value,   // [B,32,16]
             float* __restrict__ out_weight)  // [B,32,32]
{
    __shared__ float lds[LDSF];
    const int b = blockIdx.x;
    const int t = threadIdx.x;          // 256 threads = 4 waves
    const int o4 = t & 15;              // col-quad: cols orow..orow+3
    const int gp = t >> 4;              // agent pair 0..15
    const int a0 = gp * 2, a1 = a0 + 1;
    const int orow = o4 * 4;

    // ---------------- stage: S, ACT, POL (natural layouts) ----------------
    {
        const float4* src = (const float4*)(states + (size_t)b * 4096);
        #pragma unroll
        for (int r = 0; r < 4; ++r) {
            int e4 = t + r * 256;            // 1024 float4
            int a = e4 >> 5, k0 = (e4 & 31) * 4;
            *(float4*)&lds[S_O + a * 132 + k0] = src[e4];
        }
        if (t < 128) {
            *(float4*)&lds[ACT_O + t * 4] =
                ((const float4*)(actions + (size_t)b * 512))[t];
        } else {
            int u = t - 128;
            *(float4*)&lds[POL_O + u * 4] =
                ((const float4*)(policies + (size_t)b * 512))[u];
        }
    }
    __syncthreads();

    // ---- phase A: E = relu(S@WobsT+b); EA/EP = relu(S@WoaT[:,:128] + act/pol tail + b) ----
    {
        float eA0[4] = {0,0,0,0}, eA1[4] = {0,0,0,0};
        float sp0[4] = {0,0,0,0}, sp1[4] = {0,0,0,0};
        #pragma unroll 4
        for (int k = 0; k < 128; k += 4) {
            float4 s0 = *(const float4*)&lds[S_O + a0 * 132 + k];
            float4 s1 = *(const float4*)&lds[S_O + a1 * 132 + k];
            #pragma unroll
            for (int c = 0; c < 4; ++c) {
                float4 wo = *(const float4*)&W_obs[(orow + c) * 128 + k];
                float4 wa = *(const float4*)&W_oa[(orow + c) * 144 + k];
                eA0[c] = dot4(s0, wo, eA0[c]);
                eA1[c] = dot4(s1, wo, eA1[c]);
                sp0[c] = dot4(s0, wa, sp0[c]);
                sp1[c] = dot4(s1, wa, sp1[c]);
            }
        }
        float ea0[4], ea1[4], ep0[4], ep1[4];
        #pragma unroll
        for (int c = 0; c < 4; ++c) { ea0[c] = sp0[c]; ep0[c] = sp0[c]; ea1[c] = sp1[c]; ep1[c] = sp1[c]; }
        #pragma unroll
        for (int k = 0; k < 16; k += 4) {
            float4 va0 = *(const float4*)&lds[ACT_O + a0 * 16 + k];
            float4 va1 = *(const float4*)&lds[ACT_O + a1 * 16 + k];
            float4 vp0 = *(const float4*)&lds[POL_O + a0 * 16 + k];
            float4 vp1 = *(const float4*)&lds[POL_O + a1 * 16 + k];
            #pragma unroll
            for (int c = 0; c < 4; ++c) {
                float4 wa = *(const float4*)&W_oa[(orow + c) * 144 + 128 + k];
                ea0[c] = dot4(va0, wa, ea0[c]);
                ea1[c] = dot4(va1, wa, ea1[c]);
                ep0[c] = dot4(vp0, wa, ep0[c]);
                ep1[c] = dot4(vp1, wa, ep1[c]);
            }
        }
        float4 bo = *(const float4*)&b_obs[orow];
        float4 ba = *(const float4*)&b_oa[orow];
        float4 v;
        v = make_float4(fmaxf(eA0[0]+bo.x,0.f), fmaxf(eA0[1]+bo.y,0.f), fmaxf(eA0[2]+bo.z,0.f), fmaxf(eA0[3]+bo.w,0.f));
        *(float4*)&lds[E_O + a0 * 68 + orow] = v;
        v = make_float4(fmaxf(eA1[0]+bo.x,0.f), fmaxf(eA1[1]+bo.y,0.f), fmaxf(eA1[2]+bo.z,0.f), fmaxf(eA1[3]+bo.w,0.f));
        *(float4*)&lds[E_O + a1 * 68 + orow] = v;
        v = make_float4(fmaxf(ea0[0]+ba.x,0.f), fmaxf(ea0[1]+ba.y,0.f), fmaxf(ea0[2]+ba.z,0.f), fmaxf(ea0[3]+ba.w,0.f));
        *(float4*)&lds[EA_O + a0 * 68 + orow] = v;
        v = make_float4(fmaxf(ea1[0]+ba.x,0.f), fmaxf(ea1[1]+ba.y,0.f), fmaxf(ea1[2]+ba.z,0.f), fmaxf(ea1[3]+ba.w,0.f));
        *(float4*)&lds[EA_O + a1 * 68 + orow] = v;
        v = make_float4(fmaxf(ep0[0]+ba.x,0.f), fmaxf(ep0[1]+ba.y,0.f), fmaxf(ep0[2]+ba.z,0.f), fmaxf(ep0[3]+ba.w,0.f));
        *(float4*)&lds[EP_O + a0 * 68 + orow] = v;
        v = make_float4(fmaxf(ep1[0]+ba.x,0.f), fmaxf(ep1[1]+ba.y,0.f), fmaxf(ep1[2]+ba.z,0.f), fmaxf(ep1[3]+ba.w,0.f));
        *(float4*)&lds[EP_O + a1 * 68 + orow] = v;
    }
    __syncthreads();

    // ---- phase B: K = E@WkT, Q = E@WqT (overwrites S region) ----
    {
        float k0a[4] = {0,0,0,0}, k1a[4] = {0,0,0,0};
        float q0a[4] = {0,0,0,0}, q1a[4] = {0,0,0,0};
        #pragma unroll 4
        for (int k = 0; k < 64; k += 4) {
            float4 e0 = *(const float4*)&lds[E_O + a0 * 68 + k];
            float4 e1 = *(const float4*)&lds[E_O + a1 * 68 + k];
            #pragma unroll
            for (int c = 0; c < 4; ++c) {
                float4 wk = *(const float4*)&W_key[(orow + c) * 64 + k];
                float4 wq = *(const float4*)&W_query[(orow + c) * 64 + k];
                k0a[c] = dot4(e0, wk, k0a[c]);
                k1a[c] = dot4(e1, wk, k1a[c]);
                q0a[c] = dot4(e0, wq, q0a[c]);
                q1a[c] = dot4(e1, wq, q1a[c]);
            }
        }
        *(float4*)&lds[K_O + a0 * 68 + orow] = make_float4(k0a[0], k0a[1], k0a[2], k0a[3]);
        *(float4*)&lds[K_O + a1 * 68 + orow] = make_float4(k1a[0], k1a[1], k1a[2], k1a[3]);
        *(float4*)&lds[Q_O + a0 * 68 + orow] = make_float4(q0a[0], q0a[1], q0a[2], q0a[3]);
        *(float4*)&lds[Q_O + a1 * 68 + orow] = make_float4(q1a[0], q1a[1], q1a[2], q1a[3]);
    }
    __syncthreads();

    // ---- score + softmax: w[j][i] = softmax_i(q_i . k_j / 8) ----
    {
        int i4s = t & 7;     // i col-quad
        int j = t >> 3;      // row 0..31
        float acc[4] = {0,0,0,0};
        #pragma unroll 4
        for (int d = 0; d < 64; d += 4) {
            float4 kj = *(const float4*)&lds[K_O + j * 68 + d];
            #pragma unroll
            for (int c = 0; c < 4; ++c) {
                float4 qi = *(const float4*)&lds[Q_O + (i4s * 4 + c) * 68 + d];
                acc[c] = dot4(kj, qi, acc[c]);
            }
        }
        float4 a = make_float4(acc[0] * 0.125f, acc[1] * 0.125f, acc[2] * 0.125f, acc[3] * 0.125f);
        float m = fmaxf(fmaxf(a.x, a.y), fmaxf(a.z, a.w));
        #pragma unroll
        for (int off = 4; off; off >>= 1)
            m = fmaxf(m, __shfl_xor(m, off, 8));
        a.x = __expf(a.x - m); a.y = __expf(a.y - m);
        a.z = __expf(a.z - m); a.w = __expf(a.w - m);
        float s = a.x + a.y + a.z + a.w;
        #pragma unroll
        for (int off = 4; off; off >>= 1)
            s += __shfl_xor(s, off, 8);
        float inv = 1.0f / s;
        a.x *= inv; a.y *= inv; a.z *= inv; a.w *= inv;
        *(float4*)&out_weight[(size_t)b * 1024 + j * 32 + i4s * 4] = a;
        *(float4*)&lds[WT_O + j * 36 + i4s * 4] = a;
    }
    __syncthreads();

    // ---- phase C: AA/AP = tanh(EA/EP @ WavT) (overwrites K/Q region) ----
    {
        float aa0[4] = {0,0,0,0}, aa1[4] = {0,0,0,0};
        float ap0[4] = {0,0,0,0}, ap1[4] = {0,0,0,0};
        #pragma unroll 4
        for (int k = 0; k < 64; k += 4) {
            float4 x0 = *(const float4*)&lds[EA_O + a0 * 68 + k];
            float4 x1 = *(const float4*)&lds[EA_O + a1 * 68 + k];
            float4 y0 = *(const float4*)&lds[EP_O + a0 * 68 + k];
            float4 y1 = *(const float4*)&lds[EP_O + a1 * 68 + k];
            #pragma unroll
            for (int c = 0; c < 4; ++c) {
                float4 wv = *(const float4*)&W_av[(orow + c) * 64 + k];
                aa0[c] = dot4(x0, wv, aa0[c]);
                aa1[c] = dot4(x1, wv, aa1[c]);
                ap0[c] = dot4(y0, wv, ap0[c]);
                ap1[c] = dot4(y1, wv, ap1[c]);
            }
        }
        *(float4*)&lds[AA_O + a0 * 68 + orow] =
            make_float4(fast_tanh(aa0[0]), fast_tanh(aa0[1]), fast_tanh(aa0[2]), fast_tanh(aa0[3]));
        *(float4*)&lds[AA_O + a1 * 68 + orow] =
            make_float4(fast_tanh(aa1[0]), fast_tanh(aa1[1]), fast_tanh(aa1[2]), fast_tanh(aa1[3]));
        *(float4*)&lds[AP_O + a0 * 68 + orow] =
            make_float4(fast_tanh(ap0[0]), fast_tanh(ap0[1]), fast_tanh(ap0[2]), fast_tanh(ap0[3]));
        *(float4*)&lds[AP_O + a1 * 68 + orow] =
            make_float4(fast_tanh(ap1[0]), fast_tanh(ap1[1]), fast_tanh(ap1[2]), fast_tanh(ap1[3]));
    }
    __syncthreads();

    // ---- phase D: NF[j] = (1/32)(sum_i w[j,i] AA[i] + w[j,j](AP[j]-AA[j])) ----
    {
        float4 acc0 = make_float4(0,0,0,0), acc1 = make_float4(0,0,0,0);
        #pragma unroll 2
        for (int i = 0; i < 32; i += 4) {
            float4 w0 = *(const float4*)&lds[WT_O + a0 * 36 + i];
            float4 w1 = *(const float4*)&lds[WT_O + a1 * 36 + i];
            #pragma unroll
            for (int u = 0; u < 4; ++u) {
                float4 av = *(const float4*)&lds[AA_O + (i + u) * 68 + orow];
                float s0 = (u == 0) ? w0.x : (u == 1) ? w0.y : (u == 2) ? w0.z : w0.w;
                float s1 = (u == 0) ? w1.x : (u == 1) ? w1.y : (u == 2) ? w1.z : w1.w;
                acc0.x = fmaf(s0, av.x, acc0.x); acc0.y = fmaf(s0, av.y, acc0.y);
                acc0.z = fmaf(s0, av.z, acc0.z); acc0.w = fmaf(s0, av.w, acc0.w);
                acc1.x = fmaf(s1, av.x, acc1.x); acc1.y = fmaf(s1, av.y, acc1.y);
                acc1.z = fmaf(s1, av.z, acc1.z); acc1.w = fmaf(s1, av.w, acc1.w);
            }
        }
        float wd0 = lds[WT_O + a0 * 36 + a0];
        float wd1 = lds[WT_O + a1 * 36 + a1];
        float4 aa0 = *(const float4*)&lds[AA_O + a0 * 68 + orow];
        float4 ap0 = *(const float4*)&lds[AP_O + a0 * 68 + orow];
        float4 aa1 = *(const float4*)&lds[AA_O + a1 * 68 + orow];
        float4 ap1 = *(const float4*)&lds[AP_O + a1 * 68 + orow];
        acc0.x = (acc0.x + wd0 * (ap0.x - aa0.x)) * 0.03125f;
        acc0.y = (acc0.y + wd0 * (ap0.y - aa0.y)) * 0.03125f;
        acc0.z = (acc0.z + wd0 * (ap0.z - aa0.z)) * 0.03125f;
        acc0.w = (acc0.w + wd0 * (ap0.w - aa0.w)) * 0.03125f;
        acc1.x = (acc1.x + wd1 * (ap1.x - aa1.x)) * 0.03125f;
        acc1.y = (acc1.y + wd1 * (ap1.y - aa1.y)) * 0.03125f;
        acc1.z = (acc1.z + wd1 * (ap1.z - aa1.z)) * 0.03125f;
        acc1.w = (acc1.w + wd1 * (ap1.w - aa1.w)) * 0.03125f;
        __syncthreads();   // AA/AP fully consumed before NF overwrites E region? (NF_O==E_O, E dead)
        *(float4*)&lds[NF_O + a0 * 68 + orow] = acc0;
        *(float4*)&lds[NF_O + a1 * 68 + orow] = acc1;
    }
    __syncthreads();

    // ---- phase E: H = leaky_relu(NF @ Wf1T) (overwrites EA region) ----
    {
        float h0[4] = {0,0,0,0}, h1[4] = {0,0,0,0};
        #pragma unroll 4
        for (int k = 0; k < 64; k += 4) {
            float4 n0 = *(const float4*)&lds[NF_O + a0 * 68 + k];
            float4 n1 = *(const float4*)&lds[NF_O + a1 * 68 + k];
            #pragma unroll
            for (int c = 0; c < 4; ++c) {
                float4 w1 = *(const float4*)&W_f1[(orow + c) * 64 + k];
                h0[c] = dot4(n0, w1, h0[c]);
                h1[c] = dot4(n1, w1, h1[c]);
            }
        }
        float4 v0 = make_float4(fmaxf(h0[0], 0.01f*h0[0]), fmaxf(h0[1], 0.01f*h0[1]),
                                fmaxf(h0[2], 0.01f*h0[2]), fmaxf(h0[3], 0.01f*h0[3]));
        float4 v1 = make_float4(fmaxf(h1[0], 0.01f*h1[0]), fmaxf(h1[1], 0.01f*h1[1]),
                                fmaxf(h1[2], 0.01f*h1[2]), fmaxf(h1[3], 0.01f*h1[3]));
        *(float4*)&lds[H_O + a0 * 68 + orow] = v0;
        *(float4*)&lds[H_O + a1 * 68 + orow] = v1;
    }
    __syncthreads();

    // ---- phase F: value = H @ Wf2T ----
    {
        int a = t >> 3, p2 = t & 7;
        float2 acc = make_float2(0.f, 0.f);
        #pragma unroll 4
        for (int k = 0; k < 64; k += 4) {
            float4 h4 = *(const float4*)&lds[H_O + a * 68 + k];
            float4 w20 = *(const float4*)&W_f2[(p2 * 2) * 64 + k];
            float4 w21 = *(const float4*)&W_f2[(p2 * 2 + 1) * 64 + k];
            acc.x = dot4(h4, w20, acc.x);
            acc.y = dot4(h4, w21, acc.y);
        }
        *(float2*)&out_value[(size_t)b * 512 + a * 16 + p2 * 2] = acc;
    }
}

extern "C" void kernel_launch(void* const* d_in, const int* in_sizes, int n_in,
                              void* d_out, int out_size, void* d_ws, size_t ws_size,
                              hipStream_t stream) {
    const float* states   = (const float*)d_in[0];
    const float* policies = (const float*)d_in[1];
    const float* actions  = (const float*)d_in[2];
    const float* W_obs    = (const float*)d_in[3];
    const float* b_obs    = (const float*)d_in[4];
    const float* W_oa     = (const float*)d_in[5];
    const float* b_oa     = (const float*)d_in[6];
    const float* W_key    = (const float*)d_in[7];
    const float* W_query  = (const float*)d_in[8];
    const float* W_av     = (const float*)d_in[9];
    const float* W_f1     = (const float*)d_in[10];
    const float* W_f2     = (const float*)d_in[11];

    float* out_value  = (float*)d_out;                 // [512,32,16]
    float* out_weight = (float*)d_out + NB * 32 * 16;  // [512,32,32]

    critic_fused<<<NB, 256, 0, stream>>>(states, policies, actions,
                                         W_obs, b_obs, W_oa, b_oa,
                                         W_key, W_query, W_av, W_f1, W_f2,
                                         out_value, out_weight);
}

// Round 5
// 54.106 us; speedup vs baseline: 2.4794x; 2.4794x over previous
//
#include <hip/hip_runtime.h>

#define NBLK 256   // 2 batches per block

// ---- d_ws layout (floats): transposed weights W^T[k][o] ----
#define WOBS_T 0        // [128][64]
#define WOA_T  8192     // [144][64]
#define WK_T   17408    // [64][64]
#define WQ_T   21504    // [64][64]
#define WAV_T  25600    // [64][64]
#define WF1_T  29696    // [64][64]
#define WF2_T  33792    // [64][16]
#define WS_FLOATS 34816 // 139264 bytes

// ---- per-batch LDS arena (floats) ----
// KQ arena: K@0, Q@2176 (each [32] rows, stride 68) -> later AA@0, AP@2176
// E @4352 ([32][68]) -> NF
// EA @6528 -> H
// EP @8704
// WT @10880 ([32][36], natural: WT[j][i])
#define KQ_O   0
#define E_O    4352
#define EA_O   6528
#define EP_O   8704
#define WT_O   10880
#define ARENA  12032
#define LDSF   (2 * ARENA)   // 24064 floats = 96256 B (1 block/CU)

#define GETC(v, u) ((u) == 0 ? (v).x : (u) == 1 ? (v).y : (u) == 2 ? (v).z : (v).w)

// acc (float[4]) += s * w4
#define FMA4(acc, s, w4)                    \
    acc[0] = fmaf((s), (w4).x, acc[0]);     \
    acc[1] = fmaf((s), (w4).y, acc[1]);     \
    acc[2] = fmaf((s), (w4).z, acc[2]);     \
    acc[3] = fmaf((s), (w4).w, acc[3]);

__device__ __forceinline__ float dot4(float4 a, float4 b, float acc) {
    acc = fmaf(a.x, b.x, acc);
    acc = fmaf(a.y, b.y, acc);
    acc = fmaf(a.z, b.z, acc);
    acc = fmaf(a.w, b.w, acc);
    return acc;
}
__device__ __forceinline__ float fast_tanh(float x) {
    float xc = fminf(fmaxf(x, -9.0f), 9.0f);
    float e = __expf(2.0f * xc);
    return (e - 1.0f) * __builtin_amdgcn_rcpf(e + 1.0f);
}

__global__ void prep_weights(const float* __restrict__ Wobs, const float* __restrict__ Woa,
                             const float* __restrict__ Wk,   const float* __restrict__ Wq,
                             const float* __restrict__ Wav,  const float* __restrict__ Wf1,
                             const float* __restrict__ Wf2,  float* __restrict__ ws) {
    int tid = blockIdx.x * 256 + threadIdx.x;
    if (tid >= WS_FLOATS) return;
    if (tid < 8192)       { int r = tid;          int k = r >> 6, o = r & 63; ws[tid] = Wobs[o * 128 + k]; }
    else if (tid < 17408) { int r = tid - 8192;   int k = r >> 6, o = r & 63; ws[tid] = Woa[o * 144 + k]; }
    else if (tid < 21504) { int r = tid - 17408;  int k = r >> 6, o = r & 63; ws[tid] = Wk[o * 64 + k]; }
    else if (tid < 25600) { int r = tid - 21504;  int k = r >> 6, o = r & 63; ws[tid] = Wq[o * 64 + k]; }
    else if (tid < 29696) { int r = tid - 25600;  int k = r >> 6, o = r & 63; ws[tid] = Wav[o * 64 + k]; }
    else if (tid < 33792) { int r = tid - 29696;  int k = r >> 6, o = r & 63; ws[tid] = Wf1[o * 64 + k]; }
    else                  { int r = tid - 33792;  int k = r >> 4, p = r & 15; ws[tid] = Wf2[p * 64 + k]; }
}

__global__ void __launch_bounds__(256)
critic_main(const float* __restrict__ states, const float* __restrict__ policies,
            const float* __restrict__ actions, const float* __restrict__ b_obs,
            const float* __restrict__ b_oa, const float* __restrict__ ws,
            float* __restrict__ out_value,   // [B,32,16]
            float* __restrict__ out_weight)  // [B,32,32]
{
    __shared__ float lds[LDSF];
    const int t = threadIdx.x;           // 256 threads = 4 waves
    const int o4 = t & 15;               // col-quad: cols orow..orow+3
    const int gp = t >> 4;               // agent-pair 0..15
    const int a0 = gp * 2, a1 = a0 + 1;
    const int orow = o4 * 4;
    const int b0 = blockIdx.x * 2, b1 = b0 + 1;
    float* A0 = lds;
    float* A1 = lds + ARENA;

    // ---- phase A: E = relu(S@WobsT+b); EA/EP = relu(S@WoaT[:128] + act/pol tail + b) ----
    {
        float aE[2][2][4] = {};   // [batch][agent][col] (fully unrolled indices)
        float aS[2][2][4] = {};
        const float* WO = ws + WOBS_T + orow;
        const float* WA = ws + WOA_T + orow;
        const float* S00 = states + ((size_t)b0 * 32 + a0) * 128;
        const float* S01 = states + ((size_t)b0 * 32 + a1) * 128;
        const float* S10 = states + ((size_t)b1 * 32 + a0) * 128;
        const float* S11 = states + ((size_t)b1 * 32 + a1) * 128;
        #pragma unroll 2
        for (int k = 0; k < 128; k += 4) {
            float4 s00 = *(const float4*)&S00[k];
            float4 s01 = *(const float4*)&S01[k];
            float4 s10 = *(const float4*)&S10[k];
            float4 s11 = *(const float4*)&S11[k];
            #pragma unroll
            for (int u = 0; u < 4; ++u) {
                float4 wo = *(const float4*)&WO[(k + u) * 64];
                float4 wa = *(const float4*)&WA[(k + u) * 64];
                FMA4(aE[0][0], GETC(s00, u), wo);  FMA4(aS[0][0], GETC(s00, u), wa);
                FMA4(aE[0][1], GETC(s01, u), wo);  FMA4(aS[0][1], GETC(s01, u), wa);
                FMA4(aE[1][0], GETC(s10, u), wo);  FMA4(aS[1][0], GETC(s10, u), wa);
                FMA4(aE[1][1], GETC(s11, u), wo);  FMA4(aS[1][1], GETC(s11, u), wa);
            }
        }
        // tail: EA from actions, EP from policies
        float aEA[2][2][4], aEP[2][2][4];
        #pragma unroll
        for (int bt = 0; bt < 2; ++bt)
            #pragma unroll
            for (int a = 0; a < 2; ++a)
                #pragma unroll
                for (int c = 0; c < 4; ++c) {
                    aEA[bt][a][c] = aS[bt][a][c];
                    aEP[bt][a][c] = aS[bt][a][c];
                }
        const float* AC00 = actions  + ((size_t)b0 * 32 + a0) * 16;
        const float* AC01 = actions  + ((size_t)b0 * 32 + a1) * 16;
        const float* AC10 = actions  + ((size_t)b1 * 32 + a0) * 16;
        const float* AC11 = actions  + ((size_t)b1 * 32 + a1) * 16;
        const float* PL00 = policies + ((size_t)b0 * 32 + a0) * 16;
        const float* PL01 = policies + ((size_t)b0 * 32 + a1) * 16;
        const float* PL10 = policies + ((size_t)b1 * 32 + a0) * 16;
        const float* PL11 = policies + ((size_t)b1 * 32 + a1) * 16;
        #pragma unroll
        for (int k = 0; k < 16; k += 4) {
            float4 c00 = *(const float4*)&AC00[k];
            float4 c01 = *(const float4*)&AC01[k];
            float4 c10 = *(const float4*)&AC10[k];
            float4 c11 = *(const float4*)&AC11[k];
            float4 p00 = *(const float4*)&PL00[k];
            float4 p01 = *(const float4*)&PL01[k];
            float4 p10 = *(const float4*)&PL10[k];
            float4 p11 = *(const float4*)&PL11[k];
            #pragma unroll
            for (int u = 0; u < 4; ++u) {
                float4 wa = *(const float4*)&WA[(128 + k + u) * 64];
                FMA4(aEA[0][0], GETC(c00, u), wa);  FMA4(aEP[0][0], GETC(p00, u), wa);
                FMA4(aEA[0][1], GETC(c01, u), wa);  FMA4(aEP[0][1], GETC(p01, u), wa);
                FMA4(aEA[1][0], GETC(c10, u), wa);  FMA4(aEP[1][0], GETC(p10, u), wa);
                FMA4(aEA[1][1], GETC(c11, u), wa);  FMA4(aEP[1][1], GETC(p11, u), wa);
            }
        }
        float4 bo = *(const float4*)&b_obs[orow];
        float4 ba = *(const float4*)&b_oa[orow];
        #pragma unroll
        for (int bt = 0; bt < 2; ++bt) {
            float* A = bt ? A1 : A0;
            #pragma unroll
            for (int a = 0; a < 2; ++a) {
                int ag = a0 + a;
                float4 vE = make_float4(fmaxf(aE[bt][a][0] + bo.x, 0.f), fmaxf(aE[bt][a][1] + bo.y, 0.f),
                                        fmaxf(aE[bt][a][2] + bo.z, 0.f), fmaxf(aE[bt][a][3] + bo.w, 0.f));
                float4 vA = make_float4(fmaxf(aEA[bt][a][0] + ba.x, 0.f), fmaxf(aEA[bt][a][1] + ba.y, 0.f),
                                        fmaxf(aEA[bt][a][2] + ba.z, 0.f), fmaxf(aEA[bt][a][3] + ba.w, 0.f));
                float4 vP = make_float4(fmaxf(aEP[bt][a][0] + ba.x, 0.f), fmaxf(aEP[bt][a][1] + ba.y, 0.f),
                                        fmaxf(aEP[bt][a][2] + ba.z, 0.f), fmaxf(aEP[bt][a][3] + ba.w, 0.f));
                *(float4*)&A[E_O  + ag * 68 + orow] = vE;
                *(float4*)&A[EA_O + ag * 68 + orow] = vA;
                *(float4*)&A[EP_O + ag * 68 + orow] = vP;
            }
        }
    }
    __syncthreads();

    // ---- phase B: K = E@WkT, Q = E@WqT ----
    {
        float aK[2][2][4] = {}, aQ[2][2][4] = {};
        const float* WK = ws + WK_T + orow;
        const float* WQ = ws + WQ_T + orow;
        #pragma unroll 2
        for (int k = 0; k < 64; k += 4) {
            float4 e00 = *(const float4*)&A0[E_O + a0 * 68 + k];
            float4 e01 = *(const float4*)&A0[E_O + a1 * 68 + k];
            float4 e10 = *(const float4*)&A1[E_O + a0 * 68 + k];
            float4 e11 = *(const float4*)&A1[E_O + a1 * 68 + k];
            #pragma unroll
            for (int u = 0; u < 4; ++u) {
                float4 wk = *(const float4*)&WK[(k + u) * 64];
                float4 wq = *(const float4*)&WQ[(k + u) * 64];
                FMA4(aK[0][0], GETC(e00, u), wk);  FMA4(aQ[0][0], GETC(e00, u), wq);
                FMA4(aK[0][1], GETC(e01, u), wk);  FMA4(aQ[0][1], GETC(e01, u), wq);
                FMA4(aK[1][0], GETC(e10, u), wk);  FMA4(aQ[1][0], GETC(e10, u), wq);
                FMA4(aK[1][1], GETC(e11, u), wk);  FMA4(aQ[1][1], GETC(e11, u), wq);
            }
        }
        #pragma unroll
        for (int bt = 0; bt < 2; ++bt) {
            float* A = bt ? A1 : A0;
            #pragma unroll
            for (int a = 0; a < 2; ++a) {
                int ag = a0 + a;
                *(float4*)&A[KQ_O + ag * 68 + orow] =
                    make_float4(aK[bt][a][0], aK[bt][a][1], aK[bt][a][2], aK[bt][a][3]);
                *(float4*)&A[KQ_O + 2176 + ag * 68 + orow] =
                    make_float4(aQ[bt][a][0], aQ[bt][a][1], aQ[bt][a][2], aQ[bt][a][3]);
            }
        }
    }
    __syncthreads();

    // ---- score + softmax: w[j][i] = softmax_i(q_i . k_j / 8) ----
    {
        int iq = t & 7;     // i col-quad
        int j = t >> 3;     // row 0..31
        #pragma unroll
        for (int bt = 0; bt < 2; ++bt) {
            float* A = bt ? A1 : A0;
            int b = bt ? b1 : b0;
            float acc[4] = {};
            #pragma unroll 4
            for (int d = 0; d < 64; d += 4) {
                float4 kj = *(const float4*)&A[KQ_O + j * 68 + d];
                #pragma unroll
                for (int c = 0; c < 4; ++c) {
                    float4 qi = *(const float4*)&A[KQ_O + 2176 + (iq * 4 + c) * 68 + d];
                    acc[c] = dot4(kj, qi, acc[c]);
                }
            }
            float4 a = make_float4(acc[0] * 0.125f, acc[1] * 0.125f, acc[2] * 0.125f, acc[3] * 0.125f);
            float m = fmaxf(fmaxf(a.x, a.y), fmaxf(a.z, a.w));
            #pragma unroll
            for (int off = 4; off; off >>= 1)
                m = fmaxf(m, __shfl_xor(m, off, 8));
            a.x = __expf(a.x - m); a.y = __expf(a.y - m);
            a.z = __expf(a.z - m); a.w = __expf(a.w - m);
            float s = a.x + a.y + a.z + a.w;
            #pragma unroll
            for (int off = 4; off; off >>= 1)
                s += __shfl_xor(s, off, 8);
            float inv = 1.0f / s;
            a.x *= inv; a.y *= inv; a.z *= inv; a.w *= inv;
            *(float4*)&out_weight[(size_t)b * 1024 + j * 32 + iq * 4] = a;
            *(float4*)&A[WT_O + j * 36 + iq * 4] = a;   // natural WT[j][i]
        }
    }
    __syncthreads();

    // ---- phase C: AA/AP = tanh(EA/EP @ WavT) -> KQ arena ----
    {
        float aA[2][2][4] = {}, aP[2][2][4] = {};
        const float* WV = ws + WAV_T + orow;
        #pragma unroll 2
        for (int k = 0; k < 64; k += 4) {
            float4 x00 = *(const float4*)&A0[EA_O + a0 * 68 + k];
            float4 x01 = *(const float4*)&A0[EA_O + a1 * 68 + k];
            float4 x10 = *(const float4*)&A1[EA_O + a0 * 68 + k];
            float4 x11 = *(const float4*)&A1[EA_O + a1 * 68 + k];
            float4 y00 = *(const float4*)&A0[EP_O + a0 * 68 + k];
            float4 y01 = *(const float4*)&A0[EP_O + a1 * 68 + k];
            float4 y10 = *(const float4*)&A1[EP_O + a0 * 68 + k];
            float4 y11 = *(const float4*)&A1[EP_O + a1 * 68 + k];
            #pragma unroll
            for (int u = 0; u < 4; ++u) {
                float4 wv = *(const float4*)&WV[(k + u) * 64];
                FMA4(aA[0][0], GETC(x00, u), wv);  FMA4(aP[0][0], GETC(y00, u), wv);
                FMA4(aA[0][1], GETC(x01, u), wv);  FMA4(aP[0][1], GETC(y01, u), wv);
                FMA4(aA[1][0], GETC(x10, u), wv);  FMA4(aP[1][0], GETC(y10, u), wv);
                FMA4(aA[1][1], GETC(x11, u), wv);  FMA4(aP[1][1], GETC(y11, u), wv);
            }
        }
        #pragma unroll
        for (int bt = 0; bt < 2; ++bt) {
            float* A = bt ? A1 : A0;
            #pragma unroll
            for (int a = 0; a < 2; ++a) {
                int ag = a0 + a;
                *(float4*)&A[KQ_O + ag * 68 + orow] =
                    make_float4(fast_tanh(aA[bt][a][0]), fast_tanh(aA[bt][a][1]),
                                fast_tanh(aA[bt][a][2]), fast_tanh(aA[bt][a][3]));
                *(float4*)&A[KQ_O + 2176 + ag * 68 + orow] =
                    make_float4(fast_tanh(aP[bt][a][0]), fast_tanh(aP[bt][a][1]),
                                fast_tanh(aP[bt][a][2]), fast_tanh(aP[bt][a][3]));
            }
        }
    }
    __syncthreads();

    // ---- phase D: NF[j] = (1/32)(sum_i w[j,i] AA[i] + w[j,j](AP[j]-AA[j])) -> E arena ----
    {
        float acc[2][2][4] = {};
        #pragma unroll 2
        for (int i = 0; i < 32; i += 4) {
            float4 w00 = *(const float4*)&A0[WT_O + a0 * 36 + i];
            float4 w01 = *(const float4*)&A0[WT_O + a1 * 36 + i];
            float4 w10 = *(const float4*)&A1[WT_O + a0 * 36 + i];
            float4 w11 = *(const float4*)&A1[WT_O + a1 * 36 + i];
            #pragma unroll
            for (int u = 0; u < 4; ++u) {
                float4 v0 = *(const float4*)&A0[KQ_O + (i + u) * 68 + orow];
                float4 v1 = *(const float4*)&A1[KQ_O + (i + u) * 68 + orow];
                FMA4(acc[0][0], GETC(w00, u), v0);
                FMA4(acc[0][1], GETC(w01, u), v0);
                FMA4(acc[1][0], GETC(w10, u), v1);
                FMA4(acc[1][1], GETC(w11, u), v1);
            }
        }
        #pragma unroll
        for (int bt = 0; bt < 2; ++bt) {
            float* A = bt ? A1 : A0;
            #pragma unroll
            for (int a = 0; a < 2; ++a) {
                int ag = a0 + a;
                float wd = A[WT_O + ag * 36 + ag];
                float4 aa = *(const float4*)&A[KQ_O + ag * 68 + orow];
                float4 ap = *(const float4*)&A[KQ_O + 2176 + ag * 68 + orow];
                float4 v;
                v.x = (acc[bt][a][0] + wd * (ap.x - aa.x)) * 0.03125f;
                v.y = (acc[bt][a][1] + wd * (ap.y - aa.y)) * 0.03125f;
                v.z = (acc[bt][a][2] + wd * (ap.z - aa.z)) * 0.03125f;
                v.w = (acc[bt][a][3] + wd * (ap.w - aa.w)) * 0.03125f;
                *(float4*)&A[E_O + ag * 68 + orow] = v;   // NF
            }
        }
    }
    __syncthreads();

    // ---- phase E: H = leaky_relu(NF @ Wf1T) -> EA arena ----
    {
        float h[2][2][4] = {};
        const float* W1 = ws + WF1_T + orow;
        #pragma unroll 2
        for (int k = 0; k < 64; k += 4) {
            float4 n00 = *(const float4*)&A0[E_O + a0 * 68 + k];
            float4 n01 = *(const float4*)&A0[E_O + a1 * 68 + k];
            float4 n10 = *(const float4*)&A1[E_O + a0 * 68 + k];
            float4 n11 = *(const float4*)&A1[E_O + a1 * 68 + k];
            #pragma unroll
            for (int u = 0; u < 4; ++u) {
                float4 w = *(const float4*)&W1[(k + u) * 64];
                FMA4(h[0][0], GETC(n00, u), w);
                FMA4(h[0][1], GETC(n01, u), w);
                FMA4(h[1][0], GETC(n10, u), w);
                FMA4(h[1][1], GETC(n11, u), w);
            }
        }
        #pragma unroll
        for (int bt = 0; bt < 2; ++bt) {
            float* A = bt ? A1 : A0;
            #pragma unroll
            for (int a = 0; a < 2; ++a) {
                int ag = a0 + a;
                float4 v = make_float4(fmaxf(h[bt][a][0], 0.01f * h[bt][a][0]),
                                       fmaxf(h[bt][a][1], 0.01f * h[bt][a][1]),
                                       fmaxf(h[bt][a][2], 0.01f * h[bt][a][2]),
                                       fmaxf(h[bt][a][3], 0.01f * h[bt][a][3]));
                *(float4*)&A[EA_O + ag * 68 + orow] = v;   // H
            }
        }
    }
    __syncthreads();

    // ---- phase F: value = H @ Wf2T ----
    {
        int a = t >> 3, p2 = t & 7;
        #pragma unroll
        for (int bt = 0; bt < 2; ++bt) {
            float* A = bt ? A1 : A0;
            int b = bt ? b1 : b0;
            float2 acc = make_float2(0.f, 0.f);
            #pragma unroll 4
            for (int k = 0; k < 64; k += 4) {
                float4 h4 = *(const float4*)&A[EA_O + a * 68 + k];
                #pragma unroll
                for (int u = 0; u < 4; ++u) {
                    float2 w2 = *(const float2*)&ws[WF2_T + (k + u) * 16 + p2 * 2];
                    acc.x = fmaf(GETC(h4, u), w2.x, acc.x);
                    acc.y = fmaf(GETC(h4, u), w2.y, acc.y);
                }
            }
            *(float2*)&out_value[(size_t)b * 512 + a * 16 + p2 * 2] = acc;
        }
    }
}

extern "C" void kernel_launch(void* const* d_in, const int* in_sizes, int n_in,
                              void* d_out, int out_size, void* d_ws, size_t ws_size,
                              hipStream_t stream) {
    const float* states   = (const float*)d_in[0];
    const float* policies = (const float*)d_in[1];
    const float* actions  = (const float*)d_in[2];
    const float* W_obs    = (const float*)d_in[3];
    const float* b_obs    = (const float*)d_in[4];
    const float* W_oa     = (const float*)d_in[5];
    const float* b_oa     = (const float*)d_in[6];
    const float* W_key    = (const float*)d_in[7];
    const float* W_query  = (const float*)d_in[8];
    const float* W_av     = (const float*)d_in[9];
    const float* W_f1     = (const float*)d_in[10];
    const float* W_f2     = (const float*)d_in[11];

    float* ws = (float*)d_ws;
    float* out_value  = (float*)d_out;                 // [512,32,16]
    float* out_weight = (float*)d_out + 512 * 32 * 16; // [512,32,32]

    prep_weights<<<(WS_FLOATS + 255) / 256, 256, 0, stream>>>(
        W_obs, W_oa, W_key, W_query, W_av, W_f1, W_f2, ws);
    critic_main<<<NBLK, 256, 0, stream>>>(states, policies, actions,
                                          b_obs, b_oa, ws, out_value, out_weight);
}

// Round 6
// 48.041 us; speedup vs baseline: 2.7924x; 1.1262x over previous
//
#include <hip/hip_runtime.h>

#define NB 512

// ---- d_ws layout (floats): transposed weights W^T[k][o] ----
#define WOBS_T 0        // [128][64]
#define WOA_T  8192     // [144][64]
#define WK_T   17408    // [64][64]
#define WQ_T   21504    // [64][64]
#define WAV_T  25600    // [64][64]
#define WF1_T  29696    // [64][64]
#define WF2_T  33792    // [64][16]
#define WS_FLOATS 34816 // 139264 bytes

// ---- LDS arena (floats), total 16384 = 64 KiB (2 blocks/CU) ----
// R1 [4096]: S_T[128][32] -> K_T[64][32]@R1, Q_T[64][32]@R1+2048 -> H_T[64][32]@R1
// R2 [5120]: ACT_T[16][32]@R2, POL_T@R2+512, EA_T[64][32]@R2+1024, EP_T[64][32]@R2+3072
// R3 [2048]: E_T[64][32] -> NF_T[64][32]
// R4 [1024]: WT_T[32][32] (attention weights transposed: WT[i][j] = w[j][i])
// R5 [4096]: AA[32][64] natural @R5, AP[32][64] @R5+2048
#define R1 0
#define R2 4096
#define R3 9216
#define R4 11264
#define R5 12288
#define LDSF 16384

// swizzled [row][32-agent] addressing: agent-quad XOR'd with (row>>2)&7
__device__ __forceinline__ int tq(int r, int q) {
    return r * 32 + (((q ^ (r >> 2)) & 7) << 2);
}
__device__ __forceinline__ int ta(int r, int a) {
    return tq(r, a >> 2) + (a & 3);
}
// agent-pair addressing (pair gp -> agents gp*2, gp*2+1), float2-aligned
__device__ __forceinline__ int tp(int r, int gp) {
    return tq(r, gp >> 1) + ((gp & 1) * 2);
}

__device__ __forceinline__ void fma4(float4& a, float s, float4 w) {
    a.x = fmaf(s, w.x, a.x);
    a.y = fmaf(s, w.y, a.y);
    a.z = fmaf(s, w.z, a.z);
    a.w = fmaf(s, w.w, a.w);
}

#define FMA_PAIR(acc, s2, w4)                 \
    fma4(acc[0], (s2).x, (w4));               \
    fma4(acc[1], (s2).y, (w4));

// transposed store: value v (4 rows c0..c0+3) of agent a into [row][agent] array at base B
#define STT(B, c0, a, v)                          \
    lds[(B) + ta((c0) + 0, (a))] = (v).x;         \
    lds[(B) + ta((c0) + 1, (a))] = (v).y;         \
    lds[(B) + ta((c0) + 2, (a))] = (v).z;         \
    lds[(B) + ta((c0) + 3, (a))] = (v).w;

__device__ __forceinline__ float4 addrelu4(float4 v, float4 b) {
    return make_float4(fmaxf(v.x + b.x, 0.f), fmaxf(v.y + b.y, 0.f),
                       fmaxf(v.z + b.z, 0.f), fmaxf(v.w + b.w, 0.f));
}
__device__ __forceinline__ float fast_tanh(float x) {
    float xc = fminf(fmaxf(x, -9.0f), 9.0f);
    float e = __expf(2.0f * xc);
    return (e - 1.0f) * __builtin_amdgcn_rcpf(e + 1.0f);
}

__global__ void prep_weights(const float* __restrict__ Wobs, const float* __restrict__ Woa,
                             const float* __restrict__ Wk,   const float* __restrict__ Wq,
                             const float* __restrict__ Wav,  const float* __restrict__ Wf1,
                             const float* __restrict__ Wf2,  float* __restrict__ ws) {
    int tid = blockIdx.x * 256 + threadIdx.x;
    if (tid >= WS_FLOATS) return;
    if (tid < 8192)       { int r = tid;          int k = r >> 6, o = r & 63; ws[tid] = Wobs[o * 128 + k]; }
    else if (tid < 17408) { int r = tid - 8192;   int k = r >> 6, o = r & 63; ws[tid] = Woa[o * 144 + k]; }
    else if (tid < 21504) { int r = tid - 17408;  int k = r >> 6, o = r & 63; ws[tid] = Wk[o * 64 + k]; }
    else if (tid < 25600) { int r = tid - 21504;  int k = r >> 6, o = r & 63; ws[tid] = Wq[o * 64 + k]; }
    else if (tid < 29696) { int r = tid - 25600;  int k = r >> 6, o = r & 63; ws[tid] = Wav[o * 64 + k]; }
    else if (tid < 33792) { int r = tid - 29696;  int k = r >> 6, o = r & 63; ws[tid] = Wf1[o * 64 + k]; }
    else                  { int r = tid - 33792;  int k = r >> 4, p = r & 15; ws[tid] = Wf2[p * 64 + k]; }
}

__global__ void __launch_bounds__(256, 2)
critic_main(const float* __restrict__ states, const float* __restrict__ policies,
            const float* __restrict__ actions, const float* __restrict__ b_obs,
            const float* __restrict__ b_oa, const float* __restrict__ ws,
            float* __restrict__ out_value,   // [B,32,16]
            float* __restrict__ out_weight)  // [B,32,32]
{
    __shared__ float lds[LDSF];
    const int b = blockIdx.x;
    const int t = threadIdx.x;           // 256 threads = 4 waves
    const int o4 = t & 15;               // col-quad: cols o4*4..+3
    const int gp = t >> 4;               // agent-pair 0..15
    const int a0 = gp * 2, a1 = a0 + 1;

    // ---------------- stage activations (transposed+swizzled) ----------------
    {
        const float4* src = (const float4*)(states + (size_t)b * 4096);
        #pragma unroll
        for (int r = 0; r < 4; ++r) {
            int e4 = t + r * 256;               // 1024 float4
            int a = e4 >> 5, k0 = (e4 & 31) * 4;
            float4 v = src[e4];
            lds[R1 + ta(k0 + 0, a)] = v.x;
            lds[R1 + ta(k0 + 1, a)] = v.y;
            lds[R1 + ta(k0 + 2, a)] = v.z;
            lds[R1 + ta(k0 + 3, a)] = v.w;
        }
        #pragma unroll
        for (int r = 0; r < 2; ++r) {
            int e = t + r * 256;                // 512 floats each
            int a = e >> 4, k = e & 15;
            lds[R2 + ta(k, a)]       = actions[(size_t)b * 512 + e];
            lds[R2 + 512 + ta(k, a)] = policies[(size_t)b * 512 + e];
        }
    }
    __syncthreads();

    // ------------- phase A: E = relu(S@WobsT+b), EA/EP = relu(S@WoaT[:128]+tail+b) -------------
    {
        float4 accE[2], accSP[2];
        #pragma unroll
        for (int j = 0; j < 2; ++j) {
            accE[j] = make_float4(0.f, 0.f, 0.f, 0.f);
            accSP[j] = make_float4(0.f, 0.f, 0.f, 0.f);
        }
        const float* WO = ws + WOBS_T + o4 * 4;
        const float* WA = ws + WOA_T + o4 * 4;
        #pragma unroll 8
        for (int k = 0; k < 128; ++k) {
            float2 s2 = *(const float2*)&lds[R1 + tp(k, gp)];
            float4 wo = *(const float4*)&WO[k * 64];
            float4 wa = *(const float4*)&WA[k * 64];
            FMA_PAIR(accE, s2, wo);
            FMA_PAIR(accSP, s2, wa);
        }
        float4 accEA[2], accEP[2];
        #pragma unroll
        for (int j = 0; j < 2; ++j) { accEA[j] = accSP[j]; accEP[j] = accSP[j]; }
        #pragma unroll
        for (int k = 0; k < 16; ++k) {
            float2 a2 = *(const float2*)&lds[R2 + tp(k, gp)];
            float2 p2 = *(const float2*)&lds[R2 + 512 + tp(k, gp)];
            float4 w = *(const float4*)&WA[(128 + k) * 64];
            FMA_PAIR(accEA, a2, w);
            FMA_PAIR(accEP, p2, w);
        }
        float4 bo = *(const float4*)&b_obs[o4 * 4];
        float4 ba = *(const float4*)&b_oa[o4 * 4];
        float4 e0 = addrelu4(accE[0], bo),  e1 = addrelu4(accE[1], bo);
        float4 ea0 = addrelu4(accEA[0], ba), ea1 = addrelu4(accEA[1], ba);
        float4 ep0 = addrelu4(accEP[0], ba), ep1 = addrelu4(accEP[1], ba);
        STT(R3, o4 * 4, a0, e0);  STT(R3, o4 * 4, a1, e1);
        STT(R2 + 1024, o4 * 4, a0, ea0);  STT(R2 + 1024, o4 * 4, a1, ea1);
        STT(R2 + 3072, o4 * 4, a0, ep0);  STT(R2 + 3072, o4 * 4, a1, ep1);
    }
    __syncthreads();

    // ------------- merged phase BC: K=E@WkT, Q=E@WqT, AA=tanh(EA@WavT), AP=tanh(EP@WavT) -------------
    // 8 float4 accumulator chains per thread; 3 LDS b64 + 3 VMEM b128 + 24 FMA per k.
    {
        float4 aK[2], aQ[2], aA[2], aP[2];
        #pragma unroll
        for (int j = 0; j < 2; ++j) {
            aK[j] = make_float4(0.f, 0.f, 0.f, 0.f);
            aQ[j] = make_float4(0.f, 0.f, 0.f, 0.f);
            aA[j] = make_float4(0.f, 0.f, 0.f, 0.f);
            aP[j] = make_float4(0.f, 0.f, 0.f, 0.f);
        }
        const float* WK = ws + WK_T + o4 * 4;
        const float* WQ = ws + WQ_T + o4 * 4;
        const float* WV = ws + WAV_T + o4 * 4;
        #pragma unroll 4
        for (int k = 0; k < 64; ++k) {
            float2 e2 = *(const float2*)&lds[R3 + tp(k, gp)];
            float2 x2 = *(const float2*)&lds[R2 + 1024 + tp(k, gp)];
            float2 y2 = *(const float2*)&lds[R2 + 3072 + tp(k, gp)];
            float4 wk = *(const float4*)&WK[k * 64];
            float4 wq = *(const float4*)&WQ[k * 64];
            float4 wv = *(const float4*)&WV[k * 64];
            FMA_PAIR(aK, e2, wk);
            FMA_PAIR(aQ, e2, wq);
            FMA_PAIR(aA, x2, wv);
            FMA_PAIR(aP, y2, wv);
        }
        // K,Q transposed into R1 (S dead)
        STT(R1, o4 * 4, a0, aK[0]);  STT(R1, o4 * 4, a1, aK[1]);
        STT(R1 + 2048, o4 * 4, a0, aQ[0]);  STT(R1 + 2048, o4 * 4, a1, aQ[1]);
        // AA,AP natural [agent][64] into R5
        *(float4*)&lds[R5 + a0 * 64 + o4 * 4] =
            make_float4(fast_tanh(aA[0].x), fast_tanh(aA[0].y), fast_tanh(aA[0].z), fast_tanh(aA[0].w));
        *(float4*)&lds[R5 + a1 * 64 + o4 * 4] =
            make_float4(fast_tanh(aA[1].x), fast_tanh(aA[1].y), fast_tanh(aA[1].z), fast_tanh(aA[1].w));
        *(float4*)&lds[R5 + 2048 + a0 * 64 + o4 * 4] =
            make_float4(fast_tanh(aP[0].x), fast_tanh(aP[0].y), fast_tanh(aP[0].z), fast_tanh(aP[0].w));
        *(float4*)&lds[R5 + 2048 + a1 * 64 + o4 * 4] =
            make_float4(fast_tanh(aP[1].x), fast_tanh(aP[1].y), fast_tanh(aP[1].z), fast_tanh(aP[1].w));
    }
    __syncthreads();

    // ---- score + softmax: w[j][i] = softmax_i(q_i . k_j / 8) ----
    {
        int iq = t & 7;     // i col-quad
        int j = t >> 3;     // row 0..31
        float acc[4] = {0.f, 0.f, 0.f, 0.f};
        #pragma unroll 4
        for (int d = 0; d < 64; ++d) {
            float kv = lds[R1 + ta(d, j)];
            float4 q4 = *(const float4*)&lds[R1 + 2048 + tq(d, iq)];
            acc[0] = fmaf(kv, q4.x, acc[0]);
            acc[1] = fmaf(kv, q4.y, acc[1]);
            acc[2] = fmaf(kv, q4.z, acc[2]);
            acc[3] = fmaf(kv, q4.w, acc[3]);
        }
        float4 a = make_float4(acc[0] * 0.125f, acc[1] * 0.125f, acc[2] * 0.125f, acc[3] * 0.125f);
        float m = fmaxf(fmaxf(a.x, a.y), fmaxf(a.z, a.w));
        #pragma unroll
        for (int off = 4; off; off >>= 1)
            m = fmaxf(m, __shfl_xor(m, off, 8));
        a.x = __expf(a.x - m); a.y = __expf(a.y - m);
        a.z = __expf(a.z - m); a.w = __expf(a.w - m);
        float s = a.x + a.y + a.z + a.w;
        #pragma unroll
        for (int off = 4; off; off >>= 1)
            s += __shfl_xor(s, off, 8);
        float inv = 1.0f / s;
        a.x *= inv; a.y *= inv; a.z *= inv; a.w *= inv;
        *(float4*)&out_weight[(size_t)b * 1024 + j * 32 + iq * 4] = a;
        STT(R4, iq * 4, j, a);   // WT_T[i][j] = w[j][i]
    }
    __syncthreads();

    // ---- phase D: NF[j] = (1/32)(sum_i w[j,i] AA[i] + w[j,j](AP[j]-AA[j])) -> R3 (E dead) ----
    {
        float4 acc[2];
        acc[0] = make_float4(0.f, 0.f, 0.f, 0.f);
        acc[1] = make_float4(0.f, 0.f, 0.f, 0.f);
        #pragma unroll 8
        for (int i = 0; i < 32; ++i) {
            float2 w2 = *(const float2*)&lds[R4 + tp(i, gp)];   // w[a0][i], w[a1][i]
            float4 av = *(const float4*)&lds[R5 + i * 64 + o4 * 4];
            FMA_PAIR(acc, w2, av);
        }
        #pragma unroll
        for (int j = 0; j < 2; ++j) {
            int a = a0 + j;
            float wd = lds[R4 + ta(a, a)];
            float4 aa = *(const float4*)&lds[R5 + a * 64 + o4 * 4];
            float4 ap = *(const float4*)&lds[R5 + 2048 + a * 64 + o4 * 4];
            acc[j].x = (acc[j].x + wd * (ap.x - aa.x)) * 0.03125f;
            acc[j].y = (acc[j].y + wd * (ap.y - aa.y)) * 0.03125f;
            acc[j].z = (acc[j].z + wd * (ap.z - aa.z)) * 0.03125f;
            acc[j].w = (acc[j].w + wd * (ap.w - aa.w)) * 0.03125f;
        }
        STT(R3, o4 * 4, a0, acc[0]);   // NF_T
        STT(R3, o4 * 4, a1, acc[1]);
    }
    __syncthreads();

    // ---- phase E: H = leaky_relu(NF @ Wf1T) -> R1 (K/Q dead) ----
    {
        float4 acc[2];
        acc[0] = make_float4(0.f, 0.f, 0.f, 0.f);
        acc[1] = make_float4(0.f, 0.f, 0.f, 0.f);
        const float* W1 = ws + WF1_T + o4 * 4;
        #pragma unroll 8
        for (int k = 0; k < 64; ++k) {
            float2 s2 = *(const float2*)&lds[R3 + tp(k, gp)];
            float4 w = *(const float4*)&W1[k * 64];
            FMA_PAIR(acc, s2, w);
        }
        float4 h0, h1;
        h0 = make_float4(fmaxf(acc[0].x, 0.01f * acc[0].x), fmaxf(acc[0].y, 0.01f * acc[0].y),
                         fmaxf(acc[0].z, 0.01f * acc[0].z), fmaxf(acc[0].w, 0.01f * acc[0].w));
        h1 = make_float4(fmaxf(acc[1].x, 0.01f * acc[1].x), fmaxf(acc[1].y, 0.01f * acc[1].y),
                         fmaxf(acc[1].z, 0.01f * acc[1].z), fmaxf(acc[1].w, 0.01f * acc[1].w));
        STT(R1, o4 * 4, a0, h0);   // H_T[64][32]
        STT(R1, o4 * 4, a1, h1);
    }
    __syncthreads();

    // ---- phase F: value = H @ Wf2T ----
    {
        int a = t >> 3, p2 = t & 7;
        float2 acc = make_float2(0.f, 0.f);
        const float* W2 = ws + WF2_T + p2 * 2;
        #pragma unroll 8
        for (int k = 0; k < 64; ++k) {
            float hv = lds[R1 + ta(k, a)];
            float2 w = *(const float2*)&W2[k * 16];
            acc.x = fmaf(hv, w.x, acc.x);
            acc.y = fmaf(hv, w.y, acc.y);
        }
        *(float2*)&out_value[(size_t)b * 512 + a * 16 + p2 * 2] = acc;
    }
}

extern "C" void kernel_launch(void* const* d_in, const int* in_sizes, int n_in,
                              void* d_out, int out_size, void* d_ws, size_t ws_size,
                              hipStream_t stream) {
    const float* states   = (const float*)d_in[0];
    const float* policies = (const float*)d_in[1];
    const float* actions  = (const float*)d_in[2];
    const float* W_obs    = (const float*)d_in[3];
    const float* b_obs    = (const float*)d_in[4];
    const float* W_oa     = (const float*)d_in[5];
    const float* b_oa     = (const float*)d_in[6];
    const float* W_key    = (const float*)d_in[7];
    const float* W_query  = (const float*)d_in[8];
    const float* W_av     = (const float*)d_in[9];
    const float* W_f1     = (const float*)d_in[10];
    const float* W_f2     = (const float*)d_in[11];

    float* ws = (float*)d_ws;
    float* out_value  = (float*)d_out;                 // [512,32,16]
    float* out_weight = (float*)d_out + NB * 32 * 16;  // [512,32,32]

    prep_weights<<<(WS_FLOATS + 255) / 256, 256, 0, stream>>>(
        W_obs, W_oa, W_key, W_query, W_av, W_f1, W_f2, ws);
    critic_main<<<NB, 256, 0, stream>>>(states, policies, actions,
                                        b_obs, b_oa, ws, out_value, out_weight);
}

// Round 7
// 25.458 us; speedup vs baseline: 5.2695x; 1.8871x over previous
//
#include <hip/hip_runtime.h>

typedef _Float16 f16;
typedef _Float16 f16x8 __attribute__((ext_vector_type(8)));
typedef float f32x4 __attribute__((ext_vector_type(4)));

#define MFMA16(a, b, c) __builtin_amdgcn_mfma_f32_16x16x32_f16((a), (b), (c), 0, 0, 0)

// ---------------- d_ws (f16 units): fragment-linear split weights ----------------
// layout per matrix: [plane(hi,lo)][ntile][chunk][lane 0..63][8 f16]
#define WS_OBS 0        // N=64(4nt) K=128(4ch)  psz 8192
#define WS_OA  16384    // N=64(4nt) K=144->5ch  psz 10240
#define WS_K   36864    // N=64 K=64(2ch)        psz 4096
#define WS_Q   45056
#define WS_AV  53248
#define WS_F1  61440
#define WS_F2  69632    // N=16(1nt) K=64(2ch)   psz 1024
#define WS_TOT 71680    // f16 -> 143360 bytes

// ---------------- LDS (u16 units), total 36864 u16 = 73728 B ----------------
#define XS_HI 0         // states split [32][136]
#define XS_LO 4352
#define ACT_HI 8704     // act [32][40] (k>=16 zero)
#define ACT_LO 9984
#define POL_HI 11264
#define POL_LO 12544
// overlay (after phase A / BC):
#define AAT_HI 0        // AA transposed [64][40]
#define AAT_LO 2560
#define APT_HI 5120
#define APT_LO 7680
#define WM_HI 10240     // softmax w [32][40]
#define WM_LO 11520
#define WDIAG 12800     // float[32]
#define E_HI  13824     // E [32][72] -> NF reuse
#define E_LO  16128
#define EA_HI 18432     // EA -> H reuse
#define EA_LO 20736
#define EP_HI 23040
#define EP_LO 25344
#define KB_HI 27648     // K [32][72]
#define KB_LO 29952
#define QB_HI 32256     // Q [32][72]
#define QB_LO 34560
#define SMTOT 36864

__device__ __forceinline__ void split1(float v, ushort& h, ushort& lo) {
    f16 hf = (f16)v;
    float r = v - (float)hf;
    f16 lf = (f16)r;
    union { f16 f; ushort u; } a, b;
    a.f = hf; b.f = lf;
    h = a.u; lo = b.u;
}
__device__ __forceinline__ void stsplit(ushort* sm, int hib, int lob, int idx, float v) {
    ushort h, l;
    split1(v, h, l);
    sm[hib + idx] = h;
    sm[lob + idx] = l;
}
__device__ __forceinline__ float f16val(ushort u) {
    union { ushort u; f16 f; } x; x.u = u;
    return (float)x.f;
}
__device__ __forceinline__ f16x8 ldf(const ushort* sm, int off) {
    return *(const f16x8*)(sm + off);
}
__device__ __forceinline__ f16x8 ldw(const f16* wsf, int base, int psz, int nch,
                                     int p, int nt, int c, int l) {
    return *(const f16x8*)(wsf + base + p * psz + (((nt * nch + c) << 6) + l) * 8);
}
__device__ __forceinline__ float fast_tanh(float x) {
    float xc = fminf(fmaxf(x, -9.0f), 9.0f);
    float e = __expf(2.0f * xc);
    return (e - 1.0f) * __builtin_amdgcn_rcpf(e + 1.0f);
}

// ---------------- prep: split weights into fragment-linear hi/lo planes ----------------
__global__ void prep_frags(const float* __restrict__ Wobs, const float* __restrict__ Woa,
                           const float* __restrict__ Wk,   const float* __restrict__ Wq,
                           const float* __restrict__ Wav,  const float* __restrict__ Wf1,
                           const float* __restrict__ Wf2,  f16* __restrict__ wsf) {
    int tid = blockIdx.x * 256 + threadIdx.x;   // 8960 = 2 planes x 4480 groups
    if (tid >= 8960) return;
    int p = tid >= 4480 ? 1 : 0;
    int g = tid - p * 4480;
    const float* W; int base, psz, nch, Kreal, g0;
    if (g < 1024)      { W = Wobs; base = WS_OBS; psz = 8192;  nch = 4; Kreal = 128; g0 = g; }
    else if (g < 2304) { W = Woa;  base = WS_OA;  psz = 10240; nch = 5; Kreal = 144; g0 = g - 1024; }
    else if (g < 2816) { W = Wk;   base = WS_K;   psz = 4096;  nch = 2; Kreal = 64;  g0 = g - 2304; }
    else if (g < 3328) { W = Wq;   base = WS_Q;   psz = 4096;  nch = 2; Kreal = 64;  g0 = g - 2816; }
    else if (g < 3840) { W = Wav;  base = WS_AV;  psz = 4096;  nch = 2; Kreal = 64;  g0 = g - 3328; }
    else if (g < 4352) { W = Wf1;  base = WS_F1;  psz = 4096;  nch = 2; Kreal = 64;  g0 = g - 3840; }
    else               { W = Wf2;  base = WS_F2;  psz = 1024;  nch = 2; Kreal = 64;  g0 = g - 4352; }
    int l = g0 & 63, fc = g0 >> 6;
    int c = fc % nch, nt = fc / nch;
    int o = nt * 16 + (l & 15);
    int k0 = c * 32 + (l >> 4) * 8;
    f16 out[8];
    #pragma unroll
    for (int j = 0; j < 8; ++j) {
        int k = k0 + j;
        float v = (k < Kreal) ? W[o * Kreal + k] : 0.0f;
        f16 h = (f16)v;
        out[j] = p ? (f16)(v - (float)h) : h;
    }
    *(f16x8*)(wsf + base + p * psz + g0 * 8) = *(f16x8*)out;
}

__global__ void __launch_bounds__(256, 2)
critic_mfma(const float* __restrict__ states, const float* __restrict__ policies,
            const float* __restrict__ actions, const float* __restrict__ b_obs,
            const float* __restrict__ b_oa, const f16* __restrict__ wsf,
            float* __restrict__ out_value,   // [B,32,16]
            float* __restrict__ out_weight)  // [B,32,32]
{
    __shared__ ushort sm[SMTOT];
    const int b = blockIdx.x;
    const int t = threadIdx.x;
    const int wv = t >> 6, l = t & 63;
    const int lr = l & 15;        // row/col within 16-tile
    const int lg = l >> 4;        // k-group
    const int mt = wv & 1, nh = wv >> 1;
    const int m0 = mt * 16;

    // ---------------- stage: split states/act/pol into LDS planes ----------------
    {
        const float4* src = (const float4*)(states + (size_t)b * 4096);
        #pragma unroll
        for (int r4 = 0; r4 < 4; ++r4) {
            int e4 = t + r4 * 256;
            int row = e4 >> 5, k0 = (e4 & 31) * 4;
            float4 v = src[e4];
            ushort4 h, lo;
            split1(v.x, h.x, lo.x);
            split1(v.y, h.y, lo.y);
            split1(v.z, h.z, lo.z);
            split1(v.w, h.w, lo.w);
            *(ushort4*)(sm + XS_HI + row * 136 + k0) = h;
            *(ushort4*)(sm + XS_LO + row * 136 + k0) = lo;
        }
        // zero the k=16..39 pad of ACT/POL planes
        for (int i = t; i < 3072; i += 256) {
            int buf = i / 768, rem = i - buf * 768;
            int row = rem / 24, kk = 16 + rem - (rem / 24) * 24;
            int base = (buf == 0) ? ACT_HI : (buf == 1) ? ACT_LO : (buf == 2) ? POL_HI : POL_LO;
            sm[base + row * 40 + kk] = 0;
        }
        float2 av = *(const float2*)(actions + (size_t)b * 512 + t * 2);
        float2 pv = *(const float2*)(policies + (size_t)b * 512 + t * 2);
        int row = (t * 2) >> 4, k = (t * 2) & 15;
        stsplit(sm, ACT_HI, ACT_LO, row * 40 + k, av.x);
        stsplit(sm, ACT_HI, ACT_LO, row * 40 + k + 1, av.y);
        stsplit(sm, POL_HI, POL_LO, row * 40 + k, pv.x);
        stsplit(sm, POL_HI, POL_LO, row * 40 + k + 1, pv.y);
    }
    __syncthreads();

    const f32x4 Z = {0.f, 0.f, 0.f, 0.f};

    // ---------------- phase A: E = relu(S@WobsT+b); EA/EP = relu(S@WoaT + tail + b) ----------------
    {
        f16x8 aH[4], aL[4];
        #pragma unroll
        for (int c = 0; c < 4; ++c) {
            int ao = (m0 + lr) * 136 + c * 32 + lg * 8;
            aH[c] = ldf(sm, XS_HI + ao);
            aL[c] = ldf(sm, XS_LO + ao);
        }
        f32x4 accE[2] = {Z, Z}, accP[2] = {Z, Z};
        #pragma unroll
        for (int c = 0; c < 4; ++c) {
            #pragma unroll
            for (int n2 = 0; n2 < 2; ++n2) {
                int nt = nh * 2 + n2;
                f16x8 bh = ldw(wsf, WS_OBS, 8192, 4, 0, nt, c, l);
                f16x8 bl = ldw(wsf, WS_OBS, 8192, 4, 1, nt, c, l);
                f16x8 ch = ldw(wsf, WS_OA, 10240, 5, 0, nt, c, l);
                f16x8 cl = ldw(wsf, WS_OA, 10240, 5, 1, nt, c, l);
                accE[n2] = MFMA16(aH[c], bh, accE[n2]);
                accE[n2] = MFMA16(aH[c], bl, accE[n2]);
                accE[n2] = MFMA16(aL[c], bh, accE[n2]);
                accP[n2] = MFMA16(aH[c], ch, accP[n2]);
                accP[n2] = MFMA16(aH[c], cl, accP[n2]);
                accP[n2] = MFMA16(aL[c], ch, accP[n2]);
            }
        }
        // tails (K=16 zero-padded to 32): EA += act @ Woa[:,128:], EP += pol @ ...
        int to = (m0 + lr) * 40 + lg * 8;
        f16x8 tah = ldf(sm, ACT_HI + to), tal = ldf(sm, ACT_LO + to);
        f16x8 tph = ldf(sm, POL_HI + to), tpl = ldf(sm, POL_LO + to);
        f32x4 accA[2], accQ[2];
        #pragma unroll
        for (int n2 = 0; n2 < 2; ++n2) {
            int nt = nh * 2 + n2;
            f16x8 ch = ldw(wsf, WS_OA, 10240, 5, 0, nt, 4, l);
            f16x8 cl = ldw(wsf, WS_OA, 10240, 5, 1, nt, 4, l);
            accA[n2] = accP[n2];
            accA[n2] = MFMA16(tah, ch, accA[n2]);
            accA[n2] = MFMA16(tah, cl, accA[n2]);
            accA[n2] = MFMA16(tal, ch, accA[n2]);
            accQ[n2] = accP[n2];
            accQ[n2] = MFMA16(tph, ch, accQ[n2]);
            accQ[n2] = MFMA16(tph, cl, accQ[n2]);
            accQ[n2] = MFMA16(tpl, ch, accQ[n2]);
        }
        #pragma unroll
        for (int n2 = 0; n2 < 2; ++n2) {
            int col = (nh * 2 + n2) * 16 + lr;
            float bo = b_obs[col], ba = b_oa[col];
            #pragma unroll
            for (int r = 0; r < 4; ++r) {
                int row = m0 + lg * 4 + r;
                int idx = row * 72 + col;
                stsplit(sm, E_HI, E_LO, idx, fmaxf(accE[n2][r] + bo, 0.f));
                stsplit(sm, EA_HI, EA_LO, idx, fmaxf(accA[n2][r] + ba, 0.f));
                stsplit(sm, EP_HI, EP_LO, idx, fmaxf(accQ[n2][r] + ba, 0.f));
            }
        }
    }
    __syncthreads();

    // ---------------- phase BC: K=E@WkT, Q=E@WqT, AA=tanh(EA@WavT), AP=tanh(EP@WavT) ----------------
    {
        f16x8 eH[2], eL[2], xH[2], xL[2], yH[2], yL[2];
        #pragma unroll
        for (int c = 0; c < 2; ++c) {
            int ao = (m0 + lr) * 72 + c * 32 + lg * 8;
            eH[c] = ldf(sm, E_HI + ao);  eL[c] = ldf(sm, E_LO + ao);
            xH[c] = ldf(sm, EA_HI + ao); xL[c] = ldf(sm, EA_LO + ao);
            yH[c] = ldf(sm, EP_HI + ao); yL[c] = ldf(sm, EP_LO + ao);
        }
        f32x4 aK[2] = {Z, Z}, aQ[2] = {Z, Z}, aA[2] = {Z, Z}, aP[2] = {Z, Z};
        #pragma unroll
        for (int c = 0; c < 2; ++c) {
            #pragma unroll
            for (int n2 = 0; n2 < 2; ++n2) {
                int nt = nh * 2 + n2;
                f16x8 kh = ldw(wsf, WS_K, 4096, 2, 0, nt, c, l);
                f16x8 kl = ldw(wsf, WS_K, 4096, 2, 1, nt, c, l);
                f16x8 qh = ldw(wsf, WS_Q, 4096, 2, 0, nt, c, l);
                f16x8 ql = ldw(wsf, WS_Q, 4096, 2, 1, nt, c, l);
                f16x8 vh = ldw(wsf, WS_AV, 4096, 2, 0, nt, c, l);
                f16x8 vl = ldw(wsf, WS_AV, 4096, 2, 1, nt, c, l);
                aK[n2] = MFMA16(eH[c], kh, aK[n2]);
                aK[n2] = MFMA16(eH[c], kl, aK[n2]);
                aK[n2] = MFMA16(eL[c], kh, aK[n2]);
                aQ[n2] = MFMA16(eH[c], qh, aQ[n2]);
                aQ[n2] = MFMA16(eH[c], ql, aQ[n2]);
                aQ[n2] = MFMA16(eL[c], qh, aQ[n2]);
                aA[n2] = MFMA16(xH[c], vh, aA[n2]);
                aA[n2] = MFMA16(xH[c], vl, aA[n2]);
                aA[n2] = MFMA16(xL[c], vh, aA[n2]);
                aP[n2] = MFMA16(yH[c], vh, aP[n2]);
                aP[n2] = MFMA16(yH[c], vl, aP[n2]);
                aP[n2] = MFMA16(yL[c], vh, aP[n2]);
            }
        }
        #pragma unroll
        for (int n2 = 0; n2 < 2; ++n2) {
            int col = (nh * 2 + n2) * 16 + lr;
            #pragma unroll
            for (int r = 0; r < 4; ++r) {
                int row = m0 + lg * 4 + r;
                stsplit(sm, KB_HI, KB_LO, row * 72 + col, aK[n2][r]);
                stsplit(sm, QB_HI, QB_LO, row * 72 + col, aQ[n2][r]);
                // AA/AP stored transposed [col][row] for phase-D B-frags
                stsplit(sm, AAT_HI, AAT_LO, col * 40 + row, fast_tanh(aA[n2][r]));
                stsplit(sm, APT_HI, APT_LO, col * 40 + row, fast_tanh(aP[n2][r]));
            }
        }
    }
    __syncthreads();

    // ---------------- score + softmax (waves 0,1): w[j][i] = softmax_i(q_i.k_j/8) ----------------
    if (wv < 2) {
        int ms = wv * 16;
        f16x8 kH[2], kL[2];
        #pragma unroll
        for (int c = 0; c < 2; ++c) {
            int ao = (ms + lr) * 72 + c * 32 + lg * 8;
            kH[c] = ldf(sm, KB_HI + ao);
            kL[c] = ldf(sm, KB_LO + ao);
        }
        f32x4 acc[2] = {Z, Z};
        #pragma unroll
        for (int c = 0; c < 2; ++c) {
            #pragma unroll
            for (int n2 = 0; n2 < 2; ++n2) {
                int qo = (n2 * 16 + lr) * 72 + c * 32 + lg * 8;
                f16x8 qh = ldf(sm, QB_HI + qo);
                f16x8 ql = ldf(sm, QB_LO + qo);
                acc[n2] = MFMA16(kH[c], qh, acc[n2]);
                acc[n2] = MFMA16(kH[c], ql, acc[n2]);
                acc[n2] = MFMA16(kL[c], qh, acc[n2]);
            }
        }
        float* wdiag = (float*)(sm + WDIAG);
        #pragma unroll
        for (int r = 0; r < 4; ++r) {
            float v0 = acc[0][r] * 0.125f, v1 = acc[1][r] * 0.125f;
            float m = fmaxf(v0, v1);
            #pragma unroll
            for (int off = 1; off < 16; off <<= 1)
                m = fmaxf(m, __shfl_xor(m, off));
            float e0 = __expf(v0 - m), e1 = __expf(v1 - m);
            float s = e0 + e1;
            #pragma unroll
            for (int off = 1; off < 16; off <<= 1)
                s += __shfl_xor(s, off);
            float inv = 1.0f / s;
            e0 *= inv; e1 *= inv;
            int j = ms + lg * 4 + r;
            out_weight[(size_t)b * 1024 + j * 32 + lr] = e0;
            out_weight[(size_t)b * 1024 + j * 32 + 16 + lr] = e1;
            stsplit(sm, WM_HI, WM_LO, j * 40 + lr, e0);
            stsplit(sm, WM_HI, WM_LO, j * 40 + 16 + lr, e1);
            if (lr == j) wdiag[j] = e0;
            if (lr + 16 == j) wdiag[j] = e1;
        }
    }
    __syncthreads();

    // ---------------- phase D: NF[j] = (1/32)(w[j,:]@AA + w[j,j]*(AP[j]-AA[j])) ----------------
    {
        int wo = (m0 + lr) * 40 + lg * 8;
        f16x8 wh = ldf(sm, WM_HI + wo), wl = ldf(sm, WM_LO + wo);
        f32x4 acc[2] = {Z, Z};
        #pragma unroll
        for (int n2 = 0; n2 < 2; ++n2) {
            int bo2 = ((nh * 2 + n2) * 16 + lr) * 40 + lg * 8;
            f16x8 ah = ldf(sm, AAT_HI + bo2);
            f16x8 al = ldf(sm, AAT_LO + bo2);
            acc[n2] = MFMA16(wh, ah, acc[n2]);
            acc[n2] = MFMA16(wh, al, acc[n2]);
            acc[n2] = MFMA16(wl, ah, acc[n2]);
        }
        const float* wdiag = (const float*)(sm + WDIAG);
        #pragma unroll
        for (int r = 0; r < 4; ++r) {
            int j = m0 + lg * 4 + r;
            float wd = wdiag[j];
            #pragma unroll
            for (int n2 = 0; n2 < 2; ++n2) {
                int col = (nh * 2 + n2) * 16 + lr;
                float aa = f16val(sm[AAT_HI + col * 40 + j]) + f16val(sm[AAT_LO + col * 40 + j]);
                float ap = f16val(sm[APT_HI + col * 40 + j]) + f16val(sm[APT_LO + col * 40 + j]);
                float nf = (acc[n2][r] + wd * (ap - aa)) * 0.03125f;
                stsplit(sm, E_HI, E_LO, j * 72 + col, nf);   // NF in E region
            }
        }
    }
    __syncthreads();

    // ---------------- phase E: H = leaky_relu(NF @ Wf1T) ----------------
    {
        f16x8 nH[2], nL[2];
        #pragma unroll
        for (int c = 0; c < 2; ++c) {
            int ao = (m0 + lr) * 72 + c * 32 + lg * 8;
            nH[c] = ldf(sm, E_HI + ao);
            nL[c] = ldf(sm, E_LO + ao);
        }
        f32x4 acc[2] = {Z, Z};
        #pragma unroll
        for (int c = 0; c < 2; ++c) {
            #pragma unroll
            for (int n2 = 0; n2 < 2; ++n2) {
                int nt = nh * 2 + n2;
                f16x8 bh = ldw(wsf, WS_F1, 4096, 2, 0, nt, c, l);
                f16x8 bl = ldw(wsf, WS_F1, 4096, 2, 1, nt, c, l);
                acc[n2] = MFMA16(nH[c], bh, acc[n2]);
                acc[n2] = MFMA16(nH[c], bl, acc[n2]);
                acc[n2] = MFMA16(nL[c], bh, acc[n2]);
            }
        }
        #pragma unroll
        for (int n2 = 0; n2 < 2; ++n2) {
            int col = (nh * 2 + n2) * 16 + lr;
            #pragma unroll
            for (int r = 0; r < 4; ++r) {
                int row = m0 + lg * 4 + r;
                float v = acc[n2][r];
                stsplit(sm, EA_HI, EA_LO, row * 72 + col, fmaxf(v, 0.01f * v));  // H in EA region
            }
        }
    }
    __syncthreads();

    // ---------------- phase F (waves 0,1): value = H @ Wf2T ----------------
    if (wv < 2) {
        int ms = wv * 16;
        f32x4 acc = Z;
        #pragma unroll
        for (int c = 0; c < 2; ++c) {
            int ao = (ms + lr) * 72 + c * 32 + lg * 8;
            f16x8 hH = ldf(sm, EA_HI + ao);
            f16x8 hL = ldf(sm, EA_LO + ao);
            f16x8 bh = ldw(wsf, WS_F2, 1024, 2, 0, 0, c, l);
            f16x8 bl = ldw(wsf, WS_F2, 1024, 2, 1, 0, c, l);
            acc = MFMA16(hH, bh, acc);
            acc = MFMA16(hH, bl, acc);
            acc = MFMA16(hL, bh, acc);
        }
        #pragma unroll
        for (int r = 0; r < 4; ++r) {
            int j = ms + lg * 4 + r;
            out_value[(size_t)b * 512 + j * 16 + lr] = acc[r];
        }
    }
}

extern "C" void kernel_launch(void* const* d_in, const int* in_sizes, int n_in,
                              void* d_out, int out_size, void* d_ws, size_t ws_size,
                              hipStream_t stream) {
    const float* states   = (const float*)d_in[0];
    const float* policies = (const float*)d_in[1];
    const float* actions  = (const float*)d_in[2];
    const float* W_obs    = (const float*)d_in[3];
    const float* b_obs    = (const float*)d_in[4];
    const float* W_oa     = (const float*)d_in[5];
    const float* b_oa     = (const float*)d_in[6];
    const float* W_key    = (const float*)d_in[7];
    const float* W_query  = (const float*)d_in[8];
    const float* W_av     = (const float*)d_in[9];
    const float* W_f1     = (const float*)d_in[10];
    const float* W_f2     = (const float*)d_in[11];

    f16* wsf = (f16*)d_ws;
    float* out_value  = (float*)d_out;                 // [512,32,16]
    float* out_weight = (float*)d_out + 512 * 32 * 16; // [512,32,32]

    prep_frags<<<35, 256, 0, stream>>>(W_obs, W_oa, W_key, W_query, W_av, W_f1, W_f2, wsf);
    critic_mfma<<<512, 256, 0, stream>>>(states, policies, actions,
                                         b_obs, b_oa, wsf, out_value, out_weight);
}

// Round 8
// 20.575 us; speedup vs baseline: 6.5202x; 1.2373x over previous
//
#include <hip/hip_runtime.h>

typedef _Float16 f16;
typedef _Float16 f16x8 __attribute__((ext_vector_type(8)));
typedef float f32x4 __attribute__((ext_vector_type(4)));

#define MFMA16(a, b, c) __builtin_amdgcn_mfma_f32_16x16x32_f16((a), (b), (c), 0, 0, 0)

// ---------------- d_ws (f16 units): fragment-linear split weights (unchanged layout) ----------------
#define WS_OBS 0        // N=64(4nt) K=128(4ch)  psz 8192
#define WS_OA  16384    // N=64(4nt) K=144->5ch  psz 10240
#define WS_K   36864    // N=64 K=64(2ch)        psz 4096
#define WS_Q   45056
#define WS_AV  53248
#define WS_F1  61440
#define WS_F2  69632    // N=16(1nt) K=64(2ch)   psz 1024
#define WS_TOT 71680    // f16 -> 143360 bytes

// ---------------- LDS (u16 units) ----------------
#define XS_HI  0        // states split [32][136]
#define XS_LO  4352
#define E_HI   8704     // E [32][72] -> NF reuse
#define E_LO   11008
#define EA_HI  13312    // EA -> H reuse
#define EA_LO  15616
#define EP_HI  17920
#define EP_LO  20224
#define KB_HI  22528    // K [32][72]
#define KB_LO  24832
#define QB_HI  27136    // Q [32][72]
#define QB_LO  29440
#define AAT_HI 31744    // AA transposed [64][40]
#define AAT_LO 34304
#define WM_HI  36864    // softmax w [32][40]
#define WM_LO  38144
#define WDIAG  39424    // float[32]
#define SMTOT  39488    // 78976 B -> 2 blocks/CU

__device__ __forceinline__ void split1(float v, ushort& h, ushort& lo) {
    f16 hf = (f16)v;
    float r = v - (float)hf;
    f16 lf = (f16)r;
    union { f16 f; ushort u; } a, b;
    a.f = hf; b.f = lf;
    h = a.u; lo = b.u;
}
__device__ __forceinline__ void split4(f32x4 v, ushort4& h, ushort4& l) {
    split1(v[0], h.x, l.x);
    split1(v[1], h.y, l.y);
    split1(v[2], h.z, l.z);
    split1(v[3], h.w, l.w);
}
__device__ __forceinline__ void mk8(float4 a, float4 b, f16x8& hi, f16x8& lo) {
    float v[8] = {a.x, a.y, a.z, a.w, b.x, b.y, b.z, b.w};
    #pragma unroll
    for (int j = 0; j < 8; ++j) {
        f16 h = (f16)v[j];
        hi[j] = h;
        lo[j] = (f16)(v[j] - (float)h);
    }
}
__device__ __forceinline__ f16x8 ldf(const ushort* sm, int off) {
    return *(const f16x8*)(sm + off);
}
__device__ __forceinline__ f16x8 ldw(const f16* wsf, int base, int psz, int nch,
                                     int p, int nt, int c, int l) {
    return *(const f16x8*)(wsf + base + p * psz + (((nt * nch + c) << 6) + l) * 8);
}
__device__ __forceinline__ float fast_tanh(float x) {
    float xc = fminf(fmaxf(x, -9.0f), 9.0f);
    float e = __expf(2.0f * xc);
    return (e - 1.0f) * __builtin_amdgcn_rcpf(e + 1.0f);
}

// ---------------- prep: split weights into fragment-linear hi/lo planes (unchanged) ----------------
__global__ void prep_frags(const float* __restrict__ Wobs, const float* __restrict__ Woa,
                           const float* __restrict__ Wk,   const float* __restrict__ Wq,
                           const float* __restrict__ Wav,  const float* __restrict__ Wf1,
                           const float* __restrict__ Wf2,  f16* __restrict__ wsf) {
    int tid = blockIdx.x * 256 + threadIdx.x;   // 8960 = 2 planes x 4480 groups
    if (tid >= 8960) return;
    int p = tid >= 4480 ? 1 : 0;
    int g = tid - p * 4480;
    const float* W; int base, psz, nch, Kreal, g0;
    if (g < 1024)      { W = Wobs; base = WS_OBS; psz = 8192;  nch = 4; Kreal = 128; g0 = g; }
    else if (g < 2304) { W = Woa;  base = WS_OA;  psz = 10240; nch = 5; Kreal = 144; g0 = g - 1024; }
    else if (g < 2816) { W = Wk;   base = WS_K;   psz = 4096;  nch = 2; Kreal = 64;  g0 = g - 2304; }
    else if (g < 3328) { W = Wq;   base = WS_Q;   psz = 4096;  nch = 2; Kreal = 64;  g0 = g - 2816; }
    else if (g < 3840) { W = Wav;  base = WS_AV;  psz = 4096;  nch = 2; Kreal = 64;  g0 = g - 3328; }
    else if (g < 4352) { W = Wf1;  base = WS_F1;  psz = 4096;  nch = 2; Kreal = 64;  g0 = g - 3840; }
    else               { W = Wf2;  base = WS_F2;  psz = 1024;  nch = 2; Kreal = 64;  g0 = g - 4352; }
    int l = g0 & 63, fc = g0 >> 6;
    int c = fc % nch, nt = fc / nch;
    int o = nt * 16 + (l & 15);
    int k0 = c * 32 + (l >> 4) * 8;
    f16 out[8];
    #pragma unroll
    for (int j = 0; j < 8; ++j) {
        int k = k0 + j;
        float v = (k < Kreal) ? W[o * Kreal + k] : 0.0f;
        f16 h = (f16)v;
        out[j] = p ? (f16)(v - (float)h) : h;
    }
    *(f16x8*)(wsf + base + p * psz + g0 * 8) = *(f16x8*)out;
}

__global__ void __launch_bounds__(256, 2)
critic_mfma(const float* __restrict__ states, const float* __restrict__ policies,
            const float* __restrict__ actions, const float* __restrict__ b_obs,
            const float* __restrict__ b_oa, const f16* __restrict__ wsf,
            float* __restrict__ out_value,   // [B,32,16]
            float* __restrict__ out_weight)  // [B,32,32]
{
    __shared__ ushort sm[SMTOT];
    const int b = blockIdx.x;
    const int t = threadIdx.x;
    const int wv = t >> 6, l = t & 63;
    const int lr = l & 15;        // lane row/col within 16-tile
    const int lg = l >> 4;        // k-group / output reg-quad
    const int ft = wv;            // feature tile (M dim) 0..3
    const int f0 = ft * 16 + lg * 4;   // output feature quad base

    // ---- issue states loads first (LDS staging depends on them) ----
    float4 sv[4];
    {
        const float4* src = (const float4*)(states + (size_t)b * 4096);
        #pragma unroll
        for (int r4 = 0; r4 < 4; ++r4) sv[r4] = src[t + r4 * 256];
    }

    // ---- prefetch phase-A weight fragments (L2) ----
    f16x8 wObsH[4], wObsL[4], wOaH[4], wOaL[4];
    #pragma unroll
    for (int c = 0; c < 4; ++c) {
        wObsH[c] = ldw(wsf, WS_OBS, 8192, 4, 0, ft, c, l);
        wObsL[c] = ldw(wsf, WS_OBS, 8192, 4, 1, ft, c, l);
        wOaH[c]  = ldw(wsf, WS_OA, 10240, 5, 0, ft, c, l);
        wOaL[c]  = ldw(wsf, WS_OA, 10240, 5, 1, ft, c, l);
    }
    f16x8 wTailH = ldw(wsf, WS_OA, 10240, 5, 0, ft, 4, l);
    f16x8 wTailL = ldw(wsf, WS_OA, 10240, 5, 1, ft, 4, l);

    // ---- act/pol tail B-fragments built in-register (k>=16 zero) ----
    f16x8 actH[2], actL[2], polH[2], polL[2];
    #pragma unroll
    for (int at = 0; at < 2; ++at) {
        float4 a0v = make_float4(0.f, 0.f, 0.f, 0.f), a1v = a0v, p0v = a0v, p1v = a0v;
        if (lg < 2) {
            size_t base = (size_t)b * 512 + (at * 16 + lr) * 16 + lg * 8;
            a0v = *(const float4*)(actions + base);
            a1v = *(const float4*)(actions + base + 4);
            p0v = *(const float4*)(policies + base);
            p1v = *(const float4*)(policies + base + 4);
        }
        mk8(a0v, a1v, actH[at], actL[at]);
        mk8(p0v, p1v, polH[at], polL[at]);
    }

    // ---- stage states split hi/lo into LDS ----
    #pragma unroll
    for (int r4 = 0; r4 < 4; ++r4) {
        int e4 = t + r4 * 256, row = e4 >> 5, k0 = (e4 & 31) * 4;
        ushort4 h, lo;
        split1(sv[r4].x, h.x, lo.x);
        split1(sv[r4].y, h.y, lo.y);
        split1(sv[r4].z, h.z, lo.z);
        split1(sv[r4].w, h.w, lo.w);
        *(ushort4*)(sm + XS_HI + row * 136 + k0) = h;
        *(ushort4*)(sm + XS_LO + row * 136 + k0) = lo;
    }
    __syncthreads();

    const f32x4 Z = {0.f, 0.f, 0.f, 0.f};

    // ================= phase A: E = relu(S@WobsT+b); EA/EP = relu(S@WoaT + tail + b) =================
    f32x4 accE[2] = {Z, Z}, accP[2] = {Z, Z};
    #pragma unroll
    for (int c = 0; c < 4; ++c) {
        #pragma unroll
        for (int at = 0; at < 2; ++at) {
            int ao = (at * 16 + lr) * 136 + c * 32 + lg * 8;
            f16x8 xh = ldf(sm, XS_HI + ao), xl = ldf(sm, XS_LO + ao);
            accE[at] = MFMA16(wObsH[c], xh, accE[at]);
            accE[at] = MFMA16(wObsH[c], xl, accE[at]);
            accE[at] = MFMA16(wObsL[c], xh, accE[at]);
            accP[at] = MFMA16(wOaH[c], xh, accP[at]);
            accP[at] = MFMA16(wOaH[c], xl, accP[at]);
            accP[at] = MFMA16(wOaL[c], xh, accP[at]);
        }
    }
    f32x4 accEA[2], accEP[2];
    #pragma unroll
    for (int at = 0; at < 2; ++at) {
        accEA[at] = accP[at]; accEP[at] = accP[at];
        accEA[at] = MFMA16(wTailH, actH[at], accEA[at]);
        accEA[at] = MFMA16(wTailH, actL[at], accEA[at]);
        accEA[at] = MFMA16(wTailL, actH[at], accEA[at]);
        accEP[at] = MFMA16(wTailH, polH[at], accEP[at]);
        accEP[at] = MFMA16(wTailH, polL[at], accEP[at]);
        accEP[at] = MFMA16(wTailL, polH[at], accEP[at]);
    }

    // prefetch phase-BC weights while A finishes
    f16x8 wKH[2], wKL[2], wQH[2], wQL[2], wVH[2], wVL[2];
    #pragma unroll
    for (int c = 0; c < 2; ++c) {
        wKH[c] = ldw(wsf, WS_K, 4096, 2, 0, ft, c, l);
        wKL[c] = ldw(wsf, WS_K, 4096, 2, 1, ft, c, l);
        wQH[c] = ldw(wsf, WS_Q, 4096, 2, 0, ft, c, l);
        wQL[c] = ldw(wsf, WS_Q, 4096, 2, 1, ft, c, l);
        wVH[c] = ldw(wsf, WS_AV, 4096, 2, 0, ft, c, l);
        wVL[c] = ldw(wsf, WS_AV, 4096, 2, 1, ft, c, l);
    }

    {
        float4 bo = *(const float4*)&b_obs[f0];
        float4 ba = *(const float4*)&b_oa[f0];
        #pragma unroll
        for (int at = 0; at < 2; ++at) {
            int agent = at * 16 + lr;
            f32x4 e, ea, ep;
            e[0] = fmaxf(accE[at][0] + bo.x, 0.f);  e[1] = fmaxf(accE[at][1] + bo.y, 0.f);
            e[2] = fmaxf(accE[at][2] + bo.z, 0.f);  e[3] = fmaxf(accE[at][3] + bo.w, 0.f);
            ea[0] = fmaxf(accEA[at][0] + ba.x, 0.f); ea[1] = fmaxf(accEA[at][1] + ba.y, 0.f);
            ea[2] = fmaxf(accEA[at][2] + ba.z, 0.f); ea[3] = fmaxf(accEA[at][3] + ba.w, 0.f);
            ep[0] = fmaxf(accEP[at][0] + ba.x, 0.f); ep[1] = fmaxf(accEP[at][1] + ba.y, 0.f);
            ep[2] = fmaxf(accEP[at][2] + ba.z, 0.f); ep[3] = fmaxf(accEP[at][3] + ba.w, 0.f);
            ushort4 h, lo;
            split4(e, h, lo);
            *(ushort4*)(sm + E_HI + agent * 72 + f0) = h;
            *(ushort4*)(sm + E_LO + agent * 72 + f0) = lo;
            split4(ea, h, lo);
            *(ushort4*)(sm + EA_HI + agent * 72 + f0) = h;
            *(ushort4*)(sm + EA_LO + agent * 72 + f0) = lo;
            split4(ep, h, lo);
            *(ushort4*)(sm + EP_HI + agent * 72 + f0) = h;
            *(ushort4*)(sm + EP_LO + agent * 72 + f0) = lo;
        }
    }
    __syncthreads();

    // ================= phase BC: K=E@WkT, Q=E@WqT, AA/AP=tanh(EA/EP@WavT) =================
    f32x4 dDiff[2];
    {
        f32x4 aK[2] = {Z, Z}, aQ[2] = {Z, Z}, aA[2] = {Z, Z}, aP[2] = {Z, Z};
        #pragma unroll
        for (int c = 0; c < 2; ++c) {
            #pragma unroll
            for (int at = 0; at < 2; ++at) {
                int ao = (at * 16 + lr) * 72 + c * 32 + lg * 8;
                f16x8 eh = ldf(sm, E_HI + ao),  el = ldf(sm, E_LO + ao);
                f16x8 xh = ldf(sm, EA_HI + ao), xl = ldf(sm, EA_LO + ao);
                f16x8 yh = ldf(sm, EP_HI + ao), yl = ldf(sm, EP_LO + ao);
                aK[at] = MFMA16(wKH[c], eh, aK[at]);
                aK[at] = MFMA16(wKH[c], el, aK[at]);
                aK[at] = MFMA16(wKL[c], eh, aK[at]);
                aQ[at] = MFMA16(wQH[c], eh, aQ[at]);
                aQ[at] = MFMA16(wQH[c], el, aQ[at]);
                aQ[at] = MFMA16(wQL[c], eh, aQ[at]);
                aA[at] = MFMA16(wVH[c], xh, aA[at]);
                aA[at] = MFMA16(wVH[c], xl, aA[at]);
                aA[at] = MFMA16(wVL[c], xh, aA[at]);
                aP[at] = MFMA16(wVH[c], yh, aP[at]);
                aP[at] = MFMA16(wVH[c], yl, aP[at]);
                aP[at] = MFMA16(wVL[c], yh, aP[at]);
            }
        }
        #pragma unroll
        for (int at = 0; at < 2; ++at) {
            int agent = at * 16 + lr;
            ushort4 h, lo;
            split4(aK[at], h, lo);
            *(ushort4*)(sm + KB_HI + agent * 72 + f0) = h;
            *(ushort4*)(sm + KB_LO + agent * 72 + f0) = lo;
            split4(aQ[at], h, lo);
            *(ushort4*)(sm + QB_HI + agent * 72 + f0) = h;
            *(ushort4*)(sm + QB_LO + agent * 72 + f0) = lo;
            f32x4 ta, tp;
            #pragma unroll
            for (int r = 0; r < 4; ++r) {
                ta[r] = fast_tanh(aA[at][r]);
                tp[r] = fast_tanh(aP[at][r]);
            }
            dDiff[at] = tp - ta;
            #pragma unroll
            for (int r = 0; r < 4; ++r) {      // AA transposed (phase-D A-operand); AP stays in regs
                ushort hh, ll;
                split1(ta[r], hh, ll);
                sm[AAT_HI + (f0 + r) * 40 + agent] = hh;
                sm[AAT_LO + (f0 + r) * 40 + agent] = ll;
            }
        }
    }

    // prefetch phase-E/F weights
    f16x8 wF1H[2], wF1L[2], wF2H[2], wF2L[2];
    #pragma unroll
    for (int c = 0; c < 2; ++c) {
        wF1H[c] = ldw(wsf, WS_F1, 4096, 2, 0, ft, c, l);
        wF1L[c] = ldw(wsf, WS_F1, 4096, 2, 1, ft, c, l);
    }
    if (wv < 2) {
        #pragma unroll
        for (int c = 0; c < 2; ++c) {
            wF2H[c] = ldw(wsf, WS_F2, 1024, 2, 0, 0, c, l);
            wF2L[c] = ldw(wsf, WS_F2, 1024, 2, 1, 0, c, l);
        }
    }
    __syncthreads();

    // ================= score + softmax (waves 0,1): w[j][i] = softmax_i(q_i.k_j/8) =================
    if (wv < 2) {
        int jt = wv;
        f16x8 kh[2], kl[2];
        #pragma unroll
        for (int c = 0; c < 2; ++c) {
            int ko = (jt * 16 + lr) * 72 + c * 32 + lg * 8;
            kh[c] = ldf(sm, KB_HI + ko);
            kl[c] = ldf(sm, KB_LO + ko);
        }
        f32x4 s[2] = {Z, Z};
        #pragma unroll
        for (int c = 0; c < 2; ++c) {
            #pragma unroll
            for (int it = 0; it < 2; ++it) {
                int qo = (it * 16 + lr) * 72 + c * 32 + lg * 8;
                f16x8 qh = ldf(sm, QB_HI + qo), ql = ldf(sm, QB_LO + qo);
                s[it] = MFMA16(kh[c], qh, s[it]);
                s[it] = MFMA16(kh[c], ql, s[it]);
                s[it] = MFMA16(kl[c], qh, s[it]);
            }
        }
        float* wdiag = (float*)(sm + WDIAG);
        #pragma unroll
        for (int r = 0; r < 4; ++r) {
            int j = jt * 16 + lg * 4 + r;
            float v0 = s[0][r] * 0.125f, v1 = s[1][r] * 0.125f;
            float m = fmaxf(v0, v1);
            #pragma unroll
            for (int off = 1; off < 16; off <<= 1)
                m = fmaxf(m, __shfl_xor(m, off, 16));
            float e0 = __expf(v0 - m), e1 = __expf(v1 - m);
            float su = e0 + e1;
            #pragma unroll
            for (int off = 1; off < 16; off <<= 1)
                su += __shfl_xor(su, off, 16);
            float inv = 1.0f / su;
            e0 *= inv; e1 *= inv;
            out_weight[(size_t)b * 1024 + j * 32 + lr] = e0;
            out_weight[(size_t)b * 1024 + j * 32 + 16 + lr] = e1;
            ushort hh, ll;
            split1(e0, hh, ll);
            sm[WM_HI + j * 40 + lr] = hh;
            sm[WM_LO + j * 40 + lr] = ll;
            split1(e1, hh, ll);
            sm[WM_HI + j * 40 + 16 + lr] = hh;
            sm[WM_LO + j * 40 + 16 + lr] = ll;
            if (lr == lg * 4 + r) wdiag[j] = jt ? e1 : e0;
        }
    }
    __syncthreads();

    // ================= phase D: NF[j][f] = (1/32)(sum_i w[j,i]AA[i,f] + w[j,j](AP-AA)[j,f]) =================
    {
        int fo = (ft * 16 + lr) * 40 + lg * 8;
        f16x8 ah = ldf(sm, AAT_HI + fo);
        f16x8 al = ldf(sm, AAT_LO + fo);
        const float* wdiag = (const float*)(sm + WDIAG);
        #pragma unroll
        for (int jt = 0; jt < 2; ++jt) {
            int j = jt * 16 + lr;
            f16x8 wh = ldf(sm, WM_HI + j * 40 + lg * 8);
            f16x8 wl = ldf(sm, WM_LO + j * 40 + lg * 8);
            f32x4 acc = Z;
            acc = MFMA16(ah, wh, acc);
            acc = MFMA16(ah, wl, acc);
            acc = MFMA16(al, wh, acc);
            float wd = wdiag[j];
            f32x4 nf;
            #pragma unroll
            for (int r = 0; r < 4; ++r)
                nf[r] = (acc[r] + wd * dDiff[jt][r]) * 0.03125f;
            ushort4 h, lo;
            split4(nf, h, lo);
            *(ushort4*)(sm + E_HI + j * 72 + f0) = h;   // NF overwrites E (dead)
            *(ushort4*)(sm + E_LO + j * 72 + f0) = lo;
        }
    }
    __syncthreads();

    // ================= phase E: H = leaky_relu(NF @ Wf1T) =================
    {
        f32x4 hA[2] = {Z, Z};
        #pragma unroll
        for (int c = 0; c < 2; ++c) {
            #pragma unroll
            for (int jt = 0; jt < 2; ++jt) {
                int bo2 = (jt * 16 + lr) * 72 + c * 32 + lg * 8;
                f16x8 nh_ = ldf(sm, E_HI + bo2), nl_ = ldf(sm, E_LO + bo2);
                hA[jt] = MFMA16(wF1H[c], nh_, hA[jt]);
                hA[jt] = MFMA16(wF1H[c], nl_, hA[jt]);
                hA[jt] = MFMA16(wF1L[c], nh_, hA[jt]);
            }
        }
        #pragma unroll
        for (int jt = 0; jt < 2; ++jt) {
            int j = jt * 16 + lr;
            f32x4 hv;
            #pragma unroll
            for (int r = 0; r < 4; ++r)
                hv[r] = fmaxf(hA[jt][r], 0.01f * hA[jt][r]);
            ushort4 h, lo;
            split4(hv, h, lo);
            *(ushort4*)(sm + EA_HI + j * 72 + f0) = h;  // H overwrites EA (dead)
            *(ushort4*)(sm + EA_LO + j * 72 + f0) = lo;
        }
    }
    __syncthreads();

    // ================= phase F (waves 0,1): value = H @ Wf2T =================
    if (wv < 2) {
        int jt = wv;
        f32x4 acc = Z;
        #pragma unroll
        for (int c = 0; c < 2; ++c) {
            int ho = (jt * 16 + lr) * 72 + c * 32 + lg * 8;
            f16x8 hh = ldf(sm, EA_HI + ho), hl = ldf(sm, EA_LO + ho);
            acc = MFMA16(wF2H[c], hh, acc);
            acc = MFMA16(wF2H[c], hl, acc);
            acc = MFMA16(wF2L[c], hh, acc);
        }
        int j = jt * 16 + lr;
        *(float4*)&out_value[(size_t)b * 512 + j * 16 + lg * 4] =
            make_float4(acc[0], acc[1], acc[2], acc[3]);
    }
}

extern "C" void kernel_launch(void* const* d_in, const int* in_sizes, int n_in,
                              void* d_out, int out_size, void* d_ws, size_t ws_size,
                              hipStream_t stream) {
    const float* states   = (const float*)d_in[0];
    const float* policies = (const float*)d_in[1];
    const float* actions  = (const float*)d_in[2];
    const float* W_obs    = (const float*)d_in[3];
    const float* b_obs    = (const float*)d_in[4];
    const float* W_oa     = (const float*)d_in[5];
    const float* b_oa     = (const float*)d_in[6];
    const float* W_key    = (const float*)d_in[7];
    const float* W_query  = (const float*)d_in[8];
    const float* W_av     = (const float*)d_in[9];
    const float* W_f1     = (const float*)d_in[10];
    const float* W_f2     = (const float*)d_in[11];

    f16* wsf = (f16*)d_ws;
    float* out_value  = (float*)d_out;                 // [512,32,16]
    float* out_weight = (float*)d_out + 512 * 32 * 16; // [512,32,32]

    prep_frags<<<35, 256, 0, stream>>>(W_obs, W_oa, W_key, W_query, W_av, W_f1, W_f2, wsf);
    critic_mfma<<<512, 256, 0, stream>>>(states, policies, actions,
                                         b_obs, b_oa, wsf, out_value, out_weight);
}